// Round 1
// baseline (521.092 us; speedup 1.0000x reference)
//
#include <hip/hip_runtime.h>
#include <stdint.h>

#define NCLS   15
#define NTH    18
#define BATCH  16
#define NANCH  49104
#define KTOP   1000
#define NWORDS 16   // 16*64 = 1024 >= 1000

__device__ __forceinline__ float sigmoidf(float x) {
    return 1.0f / (1.0f + expf(-x));
}

__device__ __forceinline__ void levelOf(int i, int& lvl, int& h, int& s, int& pos) {
    if (i < 36864)      { lvl = 0; h = 192; s = 8;   pos = i; }
    else if (i < 46080) { lvl = 1; h = 96;  s = 16;  pos = i - 36864; }
    else if (i < 48384) { lvl = 2; h = 48;  s = 32;  pos = i - 46080; }
    else if (i < 48960) { lvl = 3; h = 24;  s = 64;  pos = i - 48384; }
    else                { lvl = 4; h = 12;  s = 128; pos = i - 48960; }
}

__device__ __forceinline__ unsigned long long shfl_u64(unsigned long long v, int src) {
    int lo = __shfl((int)(unsigned int)(v & 0xFFFFFFFFull), src);
    int hi = __shfl((int)(unsigned int)(v >> 32), src);
    return ((unsigned long long)(unsigned int)hi << 32) | (unsigned long long)(unsigned int)lo;
}

__device__ __forceinline__ unsigned long long shflxor_u64(unsigned long long v, int m) {
    int lo = __shfl_xor((int)(unsigned int)(v & 0xFFFFFFFFull), m);
    int hi = __shfl_xor((int)(unsigned int)(v >> 32), m);
    return ((unsigned long long)(unsigned int)hi << 32) | (unsigned long long)(unsigned int)lo;
}

__device__ __forceinline__ void atomicOr64Shared(unsigned long long* p, unsigned long long v) {
    unsigned int* q = (unsigned int*)p;
    unsigned int lo = (unsigned int)v;
    unsigned int hi = (unsigned int)(v >> 32);
    if (lo) atomicOr(q, lo);
    if (hi) atomicOr(q + 1, hi);
}

// ---------------- Kernel 1: per-anchor score (max sigmoid) + class (argmax+1) ----
__global__ __launch_bounds__(256) void k_scores(
    const float* __restrict__ c0, const float* __restrict__ c1,
    const float* __restrict__ c2, const float* __restrict__ c3,
    const float* __restrict__ c4,
    float* __restrict__ scores, int* __restrict__ classes)
{
    int g = blockIdx.x * 256 + threadIdx.x;
    if (g >= BATCH * NANCH) return;
    int b = g / NANCH;
    int i = g - b * NANCH;
    int lvl, h, s, pos;
    levelOf(i, lvl, h, s, pos);
    int y = pos / h, x = pos - y * h;
    int hh = h * h;
    const float* cp = (lvl == 0) ? c0 : (lvl == 1) ? c1 : (lvl == 2) ? c2 : (lvl == 3) ? c3 : c4;
    const float* base = cp + (size_t)b * NCLS * hh + (size_t)y * h + x;
    float best = -1e30f; int bc = 0;
    #pragma unroll
    for (int c = 0; c < NCLS; ++c) {
        float v = sigmoidf(base[(size_t)c * hh]);
        if (v > best) { best = v; bc = c; }
    }
    scores[g] = best;
    classes[g] = bc + 1;
}

// ---------------- Kernel 2: per-batch exact top-K (radix select + bitonic sort) --
__global__ __launch_bounds__(256) void k_topk(
    const float* __restrict__ scores,
    float* __restrict__ tsc, int* __restrict__ tix)
{
    const int b = blockIdx.x;
    const int tid = threadIdx.x;
    const float* sc = scores + (size_t)b * NANCH;

    __shared__ unsigned int hist[256];
    __shared__ unsigned int s_pref;
    __shared__ int s_k;
    __shared__ int s_cgt, s_ceq;
    __shared__ unsigned long long keys[1024];
    __shared__ int eqidx[1024];

    if (tid == 0) { s_pref = 0; s_k = KTOP; }
    __syncthreads();

    // 4-pass MSB radix select: find bits T of the K-th largest score.
    for (int pass = 0; pass < 4; ++pass) {
        hist[tid] = 0;
        __syncthreads();
        unsigned int pref = s_pref;
        int shift = 24 - pass * 8;
        unsigned int hmask = (pass == 0) ? 0u : (0xFFFFFFFFu << (shift + 8));
        for (int i = tid; i < NANCH; i += 256) {
            unsigned int bits = __float_as_uint(sc[i]);
            if ((bits & hmask) == pref)
                atomicAdd(&hist[(bits >> shift) & 0xFF], 1u);
        }
        __syncthreads();
        if (tid == 0) {
            int k = s_k;
            unsigned int cum = 0;
            for (int d = 255; d >= 0; --d) {
                unsigned int c = hist[d];
                if (cum + c >= (unsigned int)k) {
                    s_pref = pref | ((unsigned int)d << shift);
                    s_k = k - (int)cum;
                    break;
                }
                cum += c;
            }
        }
        __syncthreads();
    }
    unsigned int T = s_pref;
    int krem = s_k;     // how many == T to take (>=1)

    // init key array (pad zeros sort last: real keys have high32 >= 1)
    keys[tid] = 0ull; keys[tid + 256] = 0ull; keys[tid + 512] = 0ull; keys[tid + 768] = 0ull;
    if (tid == 0) { s_cgt = 0; s_ceq = 0; }
    __syncthreads();

    // compact: strictly-greater elements, plus list of equal-to-T elements
    for (int i = tid; i < NANCH; i += 256) {
        unsigned int bits = __float_as_uint(sc[i]);
        if (bits > T) {
            int p = atomicAdd(&s_cgt, 1);
            keys[p] = ((unsigned long long)bits << 32) |
                      (unsigned long long)(0xFFFFFFFFu - (unsigned int)i);
        } else if (bits == T) {
            int p = atomicAdd(&s_ceq, 1);
            if (p < 1024) eqidx[p] = i;
        }
    }
    __syncthreads();
    int cgt = s_cgt;
    int ceq = (s_ceq < 1024) ? s_ceq : 1024;

    // take krem smallest indices among the ties (jax top_k tie-break)
    for (int t = tid; t < ceq; t += 256) {
        int my = eqidx[t];
        int rank = 0;
        for (int j = 0; j < ceq; ++j) rank += (eqidx[j] < my) ? 1 : 0;
        if (rank < krem)
            keys[cgt + rank] = ((unsigned long long)T << 32) |
                               (unsigned long long)(0xFFFFFFFFu - (unsigned int)my);
    }
    __syncthreads();

    // bitonic sort descending over 1024 keys
    for (int sz = 2; sz <= 1024; sz <<= 1) {
        for (int st = sz >> 1; st > 0; st >>= 1) {
            for (int i = tid; i < 1024; i += 256) {
                int j = i ^ st;
                if (j > i) {
                    unsigned long long a = keys[i], c = keys[j];
                    bool desc = ((i & sz) == 0);
                    if (desc ? (a < c) : (a > c)) { keys[i] = c; keys[j] = a; }
                }
            }
            __syncthreads();
        }
    }

    for (int r = tid; r < KTOP; r += 256) {
        unsigned long long key = keys[r];
        unsigned int bits = (unsigned int)(key >> 32);
        int idx = (int)(0xFFFFFFFFu - (unsigned int)(key & 0xFFFFFFFFull));
        tsc[b * KTOP + r] = __uint_as_float(bits);
        tix[b * KTOP + r] = idx;
    }
}

// ---------------- Kernel 3: decode boxes for the selected anchors ----------------
__global__ __launch_bounds__(256) void k_decode(
    const float* __restrict__ r0, const float* __restrict__ r1,
    const float* __restrict__ r2, const float* __restrict__ r3,
    const float* __restrict__ r4,
    const float* __restrict__ t0, const float* __restrict__ t1,
    const float* __restrict__ t2, const float* __restrict__ t3,
    const float* __restrict__ t4,
    const float* __restrict__ q0, const float* __restrict__ q1,
    const float* __restrict__ q2, const float* __restrict__ q3,
    const float* __restrict__ q4,
    const int* __restrict__ tix, float* __restrict__ boxes)
{
    int g = blockIdx.x * 256 + threadIdx.x;
    if (g >= BATCH * KTOP) return;
    int b = g / KTOP;
    int idx = tix[g];
    int lvl, h, s, pos;
    levelOf(idx, lvl, h, s, pos);
    int y = pos / h, x = pos - y * h;
    int hh = h * h;
    const float* rp = (lvl == 0) ? r0 : (lvl == 1) ? r1 : (lvl == 2) ? r2 : (lvl == 3) ? r3 : r4;
    const float* tp = (lvl == 0) ? t0 : (lvl == 1) ? t1 : (lvl == 2) ? t2 : (lvl == 3) ? t3 : t4;
    const float* qp = (lvl == 0) ? q0 : (lvl == 1) ? q1 : (lvl == 2) ? q2 : (lvl == 3) ? q3 : q4;
    int off = y * h + x;

    // theta-class argmax over sigmoids (first-index tie-break)
    const float* tb = tp + (size_t)b * NTH * hh + off;
    float best = -1e30f; int bt = 0;
    #pragma unroll
    for (int c = 0; c < NTH; ++c) {
        float v = sigmoidf(tb[(size_t)c * hh]);
        if (v > best) { best = v; bt = c; }
    }
    float theta = (float)(bt + 1) * 10.0f + qp[(size_t)b * hh + off];

    const float* rb = rp + (size_t)b * 5 * hh + off;
    float fs = (float)s;
    float rr0 = rb[0] * fs;
    float rr1 = rb[(size_t)hh] * fs;
    float rr2 = rb[(size_t)2 * hh] * fs;
    float rr3 = rb[(size_t)3 * hh] * fs;
    float cx = (float)(x * s + (s >> 1));
    float cy = (float)(y * s + (s >> 1));
    float* op = boxes + (size_t)g * 5;
    op[0] = cx - rr0;
    op[1] = cy - rr1;
    op[2] = cx + rr2;
    op[3] = cy + rr3;
    op[4] = theta;
}

// ---------------- Kernel 4a: suppression bitmask (upper triangular IoU>thr) ------
__global__ __launch_bounds__(256) void k_mask(
    const float* __restrict__ boxes, unsigned long long* __restrict__ mask)
{
    int b = blockIdx.x;
    __shared__ float bx1[KTOP], by1[KTOP], bx2[KTOP], by2[KTOP], bar[KTOP];
    for (int r = threadIdx.x; r < KTOP; r += 256) {
        const float* p = boxes + ((size_t)(b * KTOP + r)) * 5;
        float x1 = p[0], y1 = p[1], x2 = p[2], y2 = p[3];
        bx1[r] = x1; by1[r] = y1; bx2[r] = x2; by2[r] = y2;
        bar[r] = fmaxf(x2 - x1, 0.0f) * fmaxf(y2 - y1, 0.0f);
    }
    __syncthreads();
    for (int i = threadIdx.x + 256 * blockIdx.y; i < KTOP; i += 1024) {
        float x1 = bx1[i], y1 = by1[i], x2 = bx2[i], y2 = by2[i], ai = bar[i];
        unsigned long long* mrow = mask + ((size_t)(b * KTOP + i)) * NWORDS;
        for (int w = 0; w < NWORDS; ++w) {
            unsigned long long m = 0ull;
            int j0 = w << 6;
            int lo = (j0 > i + 1) ? j0 : (i + 1);
            int hi = (j0 + 64 < KTOP) ? (j0 + 64) : KTOP;
            for (int j = lo; j < hi; ++j) {
                float iw = fminf(x2, bx2[j]) - fmaxf(x1, bx1[j]);
                iw = fmaxf(iw, 0.0f);
                float ih = fminf(y2, by2[j]) - fmaxf(y1, by1[j]);
                ih = fmaxf(ih, 0.0f);
                float inter = iw * ih;
                float u = ai + bar[j] - inter;
                float iou = inter / fmaxf(u, 1e-8f);
                if (iou > 0.3f) m |= (1ull << (j - j0));
            }
            mrow[w] = m;
        }
    }
}

// ---------------- Kernel 4b: greedy sequential NMS (one wave per batch) ----------
__global__ __launch_bounds__(64) void k_nms(
    const unsigned long long* __restrict__ mask,
    const float* __restrict__ tsc, int* __restrict__ keep)
{
    int b = blockIdx.x;
    int l = threadIdx.x;
    __shared__ unsigned long long sremv[NWORDS];
    __shared__ unsigned long long skeep[NWORDS];
    __shared__ unsigned long long svalid[NWORDS];

    if (l < NWORDS) sremv[l] = 0ull;
    for (int w = 0; w < NWORDS; ++w) {
        int i = (w << 6) + l;
        bool v = (i < KTOP) && (tsc[b * KTOP + i] >= 0.05f);
        unsigned long long bm = __ballot(v);
        if (l == 0) svalid[w] = bm;
    }
    __syncthreads();

    for (int w = 0; w < NWORDS; ++w) {
        int base = w << 6;
        int nrow = (KTOP - base < 64) ? (KTOP - base) : 64;
        unsigned long long rowword = 0ull;
        if (l < nrow)
            rowword = mask[((size_t)(b * KTOP + base + l)) * NWORDS + w];
        unsigned long long remw = sremv[w];
        unsigned long long validw = svalid[w];
        unsigned long long keptm = 0ull;
        for (int jj = 0; jj < nrow; ++jj) {
            if (((validw >> jj) & 1ull) && !((remw >> jj) & 1ull)) {
                keptm |= (1ull << jj);
                remw |= shfl_u64(rowword, jj);
            }
        }
        if (l == 0) skeep[w] = keptm;

        // propagate suppression from kept rows of this phase to future words
        int w2 = w + 1 + (int)(l & 15);
        unsigned long long part = 0ull;
        if (w2 < NWORDS) {
            for (int jj = (l >> 4); jj < nrow; jj += 4) {
                if ((keptm >> jj) & 1ull)
                    part |= mask[((size_t)(b * KTOP + base + jj)) * NWORDS + w2];
            }
        }
        part |= shflxor_u64(part, 16);
        part |= shflxor_u64(part, 32);
        if (w2 < NWORDS && (l >> 4) == 0 && part)
            atomicOr64Shared(&sremv[w2], part);
        __syncthreads();
    }

    for (int i = l; i < KTOP; i += 64) {
        keep[b * KTOP + i] = (int)((skeep[i >> 6] >> (i & 63)) & 1ull);
    }
}

// ---------------- Kernel 5: masked output write ----------------------------------
__global__ __launch_bounds__(256) void k_out(
    const float* __restrict__ tsc, const int* __restrict__ classes_all,
    const int* __restrict__ tix, const float* __restrict__ boxes,
    const int* __restrict__ keep, float* __restrict__ out)
{
    int g = blockIdx.x * 256 + threadIdx.x;
    if (g >= BATCH * KTOP) return;
    int b = g / KTOP;
    int k = keep[g];
    float fk = (float)k;
    out[g] = tsc[g] * fk;
    int cls = classes_all[(size_t)b * NANCH + tix[g]];
    out[BATCH * KTOP + g] = (float)(cls * k);
    const float* bp = boxes + (size_t)g * 5;
    float* op = out + 2 * BATCH * KTOP + (size_t)g * 5;
    op[0] = bp[0] * fk;
    op[1] = bp[1] * fk;
    op[2] = bp[2] * fk;
    op[3] = bp[3] * fk;
    op[4] = bp[4] * fk;
}

extern "C" void kernel_launch(void* const* d_in, const int* in_sizes, int n_in,
                              void* d_out, int out_size, void* d_ws, size_t ws_size,
                              hipStream_t stream) {
    const float* c0 = (const float*)d_in[0];
    const float* c1 = (const float*)d_in[1];
    const float* c2 = (const float*)d_in[2];
    const float* c3 = (const float*)d_in[3];
    const float* c4 = (const float*)d_in[4];
    const float* r0 = (const float*)d_in[5];
    const float* r1 = (const float*)d_in[6];
    const float* r2 = (const float*)d_in[7];
    const float* r3 = (const float*)d_in[8];
    const float* r4 = (const float*)d_in[9];
    const float* t0 = (const float*)d_in[10];
    const float* t1 = (const float*)d_in[11];
    const float* t2 = (const float*)d_in[12];
    const float* t3 = (const float*)d_in[13];
    const float* t4 = (const float*)d_in[14];
    const float* q0 = (const float*)d_in[15];
    const float* q1 = (const float*)d_in[16];
    const float* q2 = (const float*)d_in[17];
    const float* q3 = (const float*)d_in[18];
    const float* q4 = (const float*)d_in[19];

    char* ws = (char*)d_ws;
    float*              scores  = (float*)(ws + 0);
    int*                classes = (int*)(ws + 3142656);
    float*              tsc     = (float*)(ws + 6285312);
    int*                tix     = (int*)(ws + 6349312);
    float*              boxes   = (float*)(ws + 6413312);
    unsigned long long* mask    = (unsigned long long*)(ws + 6733312);
    int*                keep    = (int*)(ws + 8781312);
    float*              out     = (float*)d_out;

    k_scores<<<(BATCH * NANCH + 255) / 256, 256, 0, stream>>>(c0, c1, c2, c3, c4, scores, classes);
    k_topk<<<BATCH, 256, 0, stream>>>(scores, tsc, tix);
    k_decode<<<(BATCH * KTOP + 255) / 256, 256, 0, stream>>>(
        r0, r1, r2, r3, r4, t0, t1, t2, t3, t4, q0, q1, q2, q3, q4, tix, boxes);
    k_mask<<<dim3(BATCH, 4), 256, 0, stream>>>(boxes, mask);
    k_nms<<<BATCH, 64, 0, stream>>>(mask, tsc, keep);
    k_out<<<(BATCH * KTOP + 255) / 256, 256, 0, stream>>>(tsc, classes, tix, boxes, keep, out);
}

// Round 2
// 508.720 us; speedup vs baseline: 1.0243x; 1.0243x over previous
//
#include <hip/hip_runtime.h>
#include <stdint.h>

#define NCLS   15
#define NTH    18
#define BATCH  16
#define NANCH  49104
#define KTOP   1000
#define NWORDS 16   // 16*64 = 1024 >= 1000
#define NBIN   32768
#define BSHIFT 15
#define CAND   2048

__device__ __forceinline__ float sigmoidf(float x) {
    return 1.0f / (1.0f + expf(-x));
}

__device__ __forceinline__ void levelOf(int i, int& lvl, int& h, int& s, int& pos) {
    if (i < 36864)      { lvl = 0; h = 192; s = 8;   pos = i; }
    else if (i < 46080) { lvl = 1; h = 96;  s = 16;  pos = i - 36864; }
    else if (i < 48384) { lvl = 2; h = 48;  s = 32;  pos = i - 46080; }
    else if (i < 48960) { lvl = 3; h = 24;  s = 64;  pos = i - 48384; }
    else                { lvl = 4; h = 12;  s = 128; pos = i - 48960; }
}

__device__ __forceinline__ unsigned long long shfl_u64(unsigned long long v, int src) {
    int lo = __shfl((int)(unsigned int)(v & 0xFFFFFFFFull), src);
    int hi = __shfl((int)(unsigned int)(v >> 32), src);
    return ((unsigned long long)(unsigned int)hi << 32) | (unsigned long long)(unsigned int)lo;
}

__device__ __forceinline__ unsigned long long shflxor_u64(unsigned long long v, int m) {
    int lo = __shfl_xor((int)(unsigned int)(v & 0xFFFFFFFFull), m);
    int hi = __shfl_xor((int)(unsigned int)(v >> 32), m);
    return ((unsigned long long)(unsigned int)hi << 32) | (unsigned long long)(unsigned int)lo;
}

__device__ __forceinline__ void atomicOr64Shared(unsigned long long* p, unsigned long long v) {
    unsigned int* q = (unsigned int*)p;
    unsigned int lo = (unsigned int)v;
    unsigned int hi = (unsigned int)(v >> 32);
    if (lo) atomicOr(q, lo);
    if (hi) atomicOr(q + 1, hi);
}

// ---- Kernel 1: per-anchor score (max sigmoid) + class (argmax+1) + score hist ---
__global__ __launch_bounds__(256) void k_scores(
    const float* __restrict__ c0, const float* __restrict__ c1,
    const float* __restrict__ c2, const float* __restrict__ c3,
    const float* __restrict__ c4,
    float* __restrict__ scores, int* __restrict__ classes,
    unsigned int* __restrict__ hist)
{
    int g = blockIdx.x * 256 + threadIdx.x;
    if (g >= BATCH * NANCH) return;
    int b = g / NANCH;
    int i = g - b * NANCH;
    int lvl, h, s, pos;
    levelOf(i, lvl, h, s, pos);
    int y = pos / h, x = pos - y * h;
    int hh = h * h;
    const float* cp = (lvl == 0) ? c0 : (lvl == 1) ? c1 : (lvl == 2) ? c2 : (lvl == 3) ? c3 : c4;
    const float* base = cp + (size_t)b * NCLS * hh + (size_t)y * h + x;
    float best = -1e30f; int bc = 0;
    #pragma unroll
    for (int c = 0; c < NCLS; ++c) {
        float v = sigmoidf(base[(size_t)c * hh]);
        if (v > best) { best = v; bc = c; }
    }
    scores[g] = best;
    classes[g] = bc + 1;
    unsigned int bits = __float_as_uint(best);
    atomicAdd(&hist[(size_t)b * NBIN + (bits >> BSHIFT)], 1u);
}

// ---- Kernel 2a: find threshold bin per batch (K-th largest) ---------------------
__global__ __launch_bounds__(256) void k_findT(
    const unsigned int* __restrict__ hist, int* __restrict__ tbin)
{
    int b = blockIdx.x;
    const unsigned int* hb = hist + (size_t)b * NBIN;
    __shared__ unsigned int csum[256];
    unsigned int s = 0;
    int base = threadIdx.x * 128;
    for (int i = 0; i < 128; ++i) s += hb[base + i];
    csum[threadIdx.x] = s;
    __syncthreads();
    if (threadIdx.x == 0) {
        unsigned int cum = 0;
        int T = 0;
        for (int c = 255; c >= 0; --c) {
            if (cum + csum[c] >= (unsigned int)KTOP) {
                for (int bin = c * 128 + 127; bin >= c * 128; --bin) {
                    cum += hb[bin];
                    if (cum >= (unsigned int)KTOP) { T = bin; break; }
                }
                break;
            }
            cum += csum[c];
        }
        tbin[b] = T;
    }
}

// ---- Kernel 2b: compact candidates (bin >= threshold bin) -----------------------
__global__ __launch_bounds__(256) void k_compact(
    const float* __restrict__ scores, const int* __restrict__ tbin,
    int* __restrict__ cnt, unsigned long long* __restrict__ cand)
{
    int b = blockIdx.y;
    int i = blockIdx.x * 256 + threadIdx.x;
    if (i >= NANCH) return;
    unsigned int bits = __float_as_uint(scores[(size_t)b * NANCH + i]);
    if ((int)(bits >> BSHIFT) >= tbin[b]) {
        int pos = atomicAdd(&cnt[b], 1);
        if (pos < CAND)
            cand[(size_t)b * CAND + pos] =
                ((unsigned long long)bits << 32) |
                (unsigned long long)(0xFFFFFFFFu - (unsigned int)i);
    }
}

// ---- Kernel 2c: per-batch bitonic sort of candidates, emit exact top-K ----------
__global__ __launch_bounds__(1024) void k_sortk(
    const unsigned long long* __restrict__ cand, const int* __restrict__ cnt,
    float* __restrict__ tsc, int* __restrict__ tix)
{
    int b = blockIdx.x;
    int tid = threadIdx.x;
    __shared__ unsigned long long keys[CAND];
    int n = cnt[b]; if (n > CAND) n = CAND;
    for (int i = tid; i < CAND; i += 1024)
        keys[i] = (i < n) ? cand[(size_t)b * CAND + i] : 0ull;
    __syncthreads();
    for (int sz = 2; sz <= CAND; sz <<= 1) {
        for (int st = sz >> 1; st > 0; st >>= 1) {
            for (int i = tid; i < CAND; i += 1024) {
                int j = i ^ st;
                if (j > i) {
                    unsigned long long a = keys[i], c = keys[j];
                    bool desc = ((i & sz) == 0);
                    if (desc ? (a < c) : (a > c)) { keys[i] = c; keys[j] = a; }
                }
            }
            __syncthreads();
        }
    }
    if (tid < KTOP) {
        unsigned long long key = keys[tid];
        tsc[b * KTOP + tid] = __uint_as_float((unsigned int)(key >> 32));
        tix[b * KTOP + tid] = (int)(0xFFFFFFFFu - (unsigned int)(key & 0xFFFFFFFFull));
    }
}

// ---------------- Kernel 3: decode boxes for the selected anchors ----------------
__global__ __launch_bounds__(256) void k_decode(
    const float* __restrict__ r0, const float* __restrict__ r1,
    const float* __restrict__ r2, const float* __restrict__ r3,
    const float* __restrict__ r4,
    const float* __restrict__ t0, const float* __restrict__ t1,
    const float* __restrict__ t2, const float* __restrict__ t3,
    const float* __restrict__ t4,
    const float* __restrict__ q0, const float* __restrict__ q1,
    const float* __restrict__ q2, const float* __restrict__ q3,
    const float* __restrict__ q4,
    const int* __restrict__ tix, float* __restrict__ boxes)
{
    int g = blockIdx.x * 256 + threadIdx.x;
    if (g >= BATCH * KTOP) return;
    int b = g / KTOP;
    int idx = tix[g];
    int lvl, h, s, pos;
    levelOf(idx, lvl, h, s, pos);
    int y = pos / h, x = pos - y * h;
    int hh = h * h;
    const float* rp = (lvl == 0) ? r0 : (lvl == 1) ? r1 : (lvl == 2) ? r2 : (lvl == 3) ? r3 : r4;
    const float* tp = (lvl == 0) ? t0 : (lvl == 1) ? t1 : (lvl == 2) ? t2 : (lvl == 3) ? t3 : t4;
    const float* qp = (lvl == 0) ? q0 : (lvl == 1) ? q1 : (lvl == 2) ? q2 : (lvl == 3) ? q3 : q4;
    int off = y * h + x;

    const float* tb = tp + (size_t)b * NTH * hh + off;
    float best = -1e30f; int bt = 0;
    #pragma unroll
    for (int c = 0; c < NTH; ++c) {
        float v = sigmoidf(tb[(size_t)c * hh]);
        if (v > best) { best = v; bt = c; }
    }
    float theta = (float)(bt + 1) * 10.0f + qp[(size_t)b * hh + off];

    const float* rb = rp + (size_t)b * 5 * hh + off;
    float fs = (float)s;
    float rr0 = rb[0] * fs;
    float rr1 = rb[(size_t)hh] * fs;
    float rr2 = rb[(size_t)2 * hh] * fs;
    float rr3 = rb[(size_t)3 * hh] * fs;
    float cx = (float)(x * s + (s >> 1));
    float cy = (float)(y * s + (s >> 1));
    float* op = boxes + (size_t)g * 5;
    op[0] = cx - rr0;
    op[1] = cy - rr1;
    op[2] = cx + rr2;
    op[3] = cy + rr3;
    op[4] = theta;
}

// ---------------- Kernel 4a: suppression bitmask (upper triangular IoU>thr) ------
__global__ __launch_bounds__(256) void k_mask(
    const float* __restrict__ boxes, unsigned long long* __restrict__ mask)
{
    int b = blockIdx.x;
    __shared__ float bx1[KTOP], by1[KTOP], bx2[KTOP], by2[KTOP], bar[KTOP];
    for (int r = threadIdx.x; r < KTOP; r += 256) {
        const float* p = boxes + ((size_t)(b * KTOP + r)) * 5;
        float x1 = p[0], y1 = p[1], x2 = p[2], y2 = p[3];
        bx1[r] = x1; by1[r] = y1; bx2[r] = x2; by2[r] = y2;
        bar[r] = fmaxf(x2 - x1, 0.0f) * fmaxf(y2 - y1, 0.0f);
    }
    __syncthreads();
    for (int i = threadIdx.x + 256 * blockIdx.y; i < KTOP; i += 1024) {
        float x1 = bx1[i], y1 = by1[i], x2 = bx2[i], y2 = by2[i], ai = bar[i];
        unsigned long long* mrow = mask + ((size_t)(b * KTOP + i)) * NWORDS;
        for (int w = 0; w < NWORDS; ++w) {
            unsigned long long m = 0ull;
            int j0 = w << 6;
            int lo = (j0 > i + 1) ? j0 : (i + 1);
            int hi = (j0 + 64 < KTOP) ? (j0 + 64) : KTOP;
            for (int j = lo; j < hi; ++j) {
                float iw = fminf(x2, bx2[j]) - fmaxf(x1, bx1[j]);
                iw = fmaxf(iw, 0.0f);
                float ih = fminf(y2, by2[j]) - fmaxf(y1, by1[j]);
                ih = fmaxf(ih, 0.0f);
                float inter = iw * ih;
                float u = ai + bar[j] - inter;
                float iou = inter / fmaxf(u, 1e-8f);
                if (iou > 0.3f) m |= (1ull << (j - j0));
            }
            mrow[w] = m;
        }
    }
}

// ---------------- Kernel 4b: greedy sequential NMS (one wave per batch) ----------
__global__ __launch_bounds__(64) void k_nms(
    const unsigned long long* __restrict__ mask,
    const float* __restrict__ tsc, int* __restrict__ keep)
{
    int b = blockIdx.x;
    int l = threadIdx.x;
    __shared__ unsigned long long sremv[NWORDS];
    __shared__ unsigned long long skeep[NWORDS];
    __shared__ unsigned long long svalid[NWORDS];

    if (l < NWORDS) sremv[l] = 0ull;
    for (int w = 0; w < NWORDS; ++w) {
        int i = (w << 6) + l;
        bool v = (i < KTOP) && (tsc[b * KTOP + i] >= 0.05f);
        unsigned long long bm = __ballot(v);
        if (l == 0) svalid[w] = bm;
    }
    __syncthreads();

    for (int w = 0; w < NWORDS; ++w) {
        int base = w << 6;
        int nrow = (KTOP - base < 64) ? (KTOP - base) : 64;
        unsigned long long rowword = 0ull;
        if (l < nrow)
            rowword = mask[((size_t)(b * KTOP + base + l)) * NWORDS + w];
        unsigned long long remw = sremv[w];
        unsigned long long validw = svalid[w];
        unsigned long long keptm = 0ull;
        for (int jj = 0; jj < nrow; ++jj) {
            if (((validw >> jj) & 1ull) && !((remw >> jj) & 1ull)) {
                keptm |= (1ull << jj);
                remw |= shfl_u64(rowword, jj);
            }
        }
        if (l == 0) skeep[w] = keptm;

        int w2 = w + 1 + (int)(l & 15);
        unsigned long long part = 0ull;
        if (w2 < NWORDS) {
            for (int jj = (l >> 4); jj < nrow; jj += 4) {
                if ((keptm >> jj) & 1ull)
                    part |= mask[((size_t)(b * KTOP + base + jj)) * NWORDS + w2];
            }
        }
        part |= shflxor_u64(part, 16);
        part |= shflxor_u64(part, 32);
        if (w2 < NWORDS && (l >> 4) == 0 && part)
            atomicOr64Shared(&sremv[w2], part);
        __syncthreads();
    }

    for (int i = l; i < KTOP; i += 64) {
        keep[b * KTOP + i] = (int)((skeep[i >> 6] >> (i & 63)) & 1ull);
    }
}

// ---------------- Kernel 5: masked output write ----------------------------------
__global__ __launch_bounds__(256) void k_out(
    const float* __restrict__ tsc, const int* __restrict__ classes_all,
    const int* __restrict__ tix, const float* __restrict__ boxes,
    const int* __restrict__ keep, float* __restrict__ out)
{
    int g = blockIdx.x * 256 + threadIdx.x;
    if (g >= BATCH * KTOP) return;
    int b = g / KTOP;
    int k = keep[g];
    float fk = (float)k;
    out[g] = tsc[g] * fk;
    int cls = classes_all[(size_t)b * NANCH + tix[g]];
    out[BATCH * KTOP + g] = (float)(cls * k);
    const float* bp = boxes + (size_t)g * 5;
    float* op = out + 2 * BATCH * KTOP + (size_t)g * 5;
    op[0] = bp[0] * fk;
    op[1] = bp[1] * fk;
    op[2] = bp[2] * fk;
    op[3] = bp[3] * fk;
    op[4] = bp[4] * fk;
}

extern "C" void kernel_launch(void* const* d_in, const int* in_sizes, int n_in,
                              void* d_out, int out_size, void* d_ws, size_t ws_size,
                              hipStream_t stream) {
    const float* c0 = (const float*)d_in[0];
    const float* c1 = (const float*)d_in[1];
    const float* c2 = (const float*)d_in[2];
    const float* c3 = (const float*)d_in[3];
    const float* c4 = (const float*)d_in[4];
    const float* r0 = (const float*)d_in[5];
    const float* r1 = (const float*)d_in[6];
    const float* r2 = (const float*)d_in[7];
    const float* r3 = (const float*)d_in[8];
    const float* r4 = (const float*)d_in[9];
    const float* t0 = (const float*)d_in[10];
    const float* t1 = (const float*)d_in[11];
    const float* t2 = (const float*)d_in[12];
    const float* t3 = (const float*)d_in[13];
    const float* t4 = (const float*)d_in[14];
    const float* q0 = (const float*)d_in[15];
    const float* q1 = (const float*)d_in[16];
    const float* q2 = (const float*)d_in[17];
    const float* q3 = (const float*)d_in[18];
    const float* q4 = (const float*)d_in[19];

    // Workspace layout (max offset used: 8,845,312 B — same as the proven round-0
    // footprint). hist/cand/tcnt/tbin alias later-stage buffers; strict stream
    // ordering makes every alias safe (producer of the later buffer runs only
    // after the aliased early buffer's last consumer).
    char* ws = (char*)d_ws;
    float*              scores  = (float*)(ws + 0);          // 3,142,656
    int*                classes = (int*)(ws + 3142656);      // 3,142,656
    float*              tsc     = (float*)(ws + 6285312);    //    64,000
    int*                tix     = (int*)(ws + 6349312);      //    64,000
    float*              boxes   = (float*)(ws + 6413312);    //   320,000
    unsigned long long* cand    = (unsigned long long*)(ws + 6413312); // 262,144 (aliases boxes; consumed by k_sortk before k_decode)
    unsigned long long* mask    = (unsigned long long*)(ws + 6733312); // 2,048,000
    unsigned int*       hist    = (unsigned int*)(ws + 6733312);       // 2,097,152 (aliases mask+keep; consumed by k_findT before k_mask)
    int*                keep    = (int*)(ws + 8781312);      //    64,000
    int*                tcnt    = (int*)(ws + 8830464);      //        64 (aliases keep tail; consumed before k_nms)
    int*                tbin    = (int*)(ws + 8830528);      //        64
    float*              out     = (float*)d_out;

    // zero hist + tcnt (2,097,152 + 64 B, contiguous)
    hipMemsetAsync(ws + 6733312, 0, 2097216, stream);

    k_scores<<<(BATCH * NANCH + 255) / 256, 256, 0, stream>>>(
        c0, c1, c2, c3, c4, scores, classes, hist);
    k_findT<<<BATCH, 256, 0, stream>>>(hist, tbin);
    k_compact<<<dim3((NANCH + 255) / 256, BATCH), 256, 0, stream>>>(scores, tbin, tcnt, cand);
    k_sortk<<<BATCH, 1024, 0, stream>>>(cand, tcnt, tsc, tix);
    k_decode<<<(BATCH * KTOP + 255) / 256, 256, 0, stream>>>(
        r0, r1, r2, r3, r4, t0, t1, t2, t3, t4, q0, q1, q2, q3, q4, tix, boxes);
    k_mask<<<dim3(BATCH, 4), 256, 0, stream>>>(boxes, mask);
    k_nms<<<BATCH, 64, 0, stream>>>(mask, tsc, keep);
    k_out<<<(BATCH * KTOP + 255) / 256, 256, 0, stream>>>(tsc, classes, tix, boxes, keep, out);
}

// Round 3
// 408.492 us; speedup vs baseline: 1.2756x; 1.2454x over previous
//
#include <hip/hip_runtime.h>
#include <stdint.h>

#define NCLS   15
#define NTH    18
#define BATCH  16
#define NANCH  49104
#define KTOP   1000
#define NWORDS 16   // 16*64 = 1024 >= 1000
#define NBIN   32768
#define BSHIFT 15
#define CAND   2048

__device__ __forceinline__ float sigmoidf(float x) {
    return 1.0f / (1.0f + expf(-x));
}

__device__ __forceinline__ void levelOf(int i, int& lvl, int& h, int& s, int& pos) {
    if (i < 36864)      { lvl = 0; h = 192; s = 8;   pos = i; }
    else if (i < 46080) { lvl = 1; h = 96;  s = 16;  pos = i - 36864; }
    else if (i < 48384) { lvl = 2; h = 48;  s = 32;  pos = i - 46080; }
    else if (i < 48960) { lvl = 3; h = 24;  s = 64;  pos = i - 48384; }
    else                { lvl = 4; h = 12;  s = 128; pos = i - 48960; }
}

__device__ __forceinline__ unsigned long long shfl_u64(unsigned long long v, int src) {
    int lo = __shfl((int)(unsigned int)(v & 0xFFFFFFFFull), src);
    int hi = __shfl((int)(unsigned int)(v >> 32), src);
    return ((unsigned long long)(unsigned int)hi << 32) | (unsigned long long)(unsigned int)lo;
}

__device__ __forceinline__ unsigned long long shflxor_u64(unsigned long long v, int m) {
    int lo = __shfl_xor((int)(unsigned int)(v & 0xFFFFFFFFull), m);
    int hi = __shfl_xor((int)(unsigned int)(v >> 32), m);
    return ((unsigned long long)(unsigned int)hi << 32) | (unsigned long long)(unsigned int)lo;
}

__device__ __forceinline__ void atomicOr64Shared(unsigned long long* p, unsigned long long v) {
    unsigned int* q = (unsigned int*)p;
    unsigned int lo = (unsigned int)v;
    unsigned int hi = (unsigned int)(v >> 32);
    if (lo) atomicOr(q, lo);
    if (hi) atomicOr(q + 1, hi);
}

// ---- Kernel 1: per-anchor score = sigmoid(max logit), float4, + score hist ------
// max_i sigmoid(x_i) == sigmoid(max_i x_i) bitwise (monotone fp composition);
// the tie-sensitive argmax (class id) is computed exactly in k_decode.
__global__ __launch_bounds__(256) void k_scores(
    const float* __restrict__ c0, const float* __restrict__ c1,
    const float* __restrict__ c2, const float* __restrict__ c3,
    const float* __restrict__ c4,
    float* __restrict__ scores, unsigned int* __restrict__ hist)
{
    int g4 = blockIdx.x * 256 + threadIdx.x;
    if (g4 >= BATCH * NANCH / 4) return;
    int g = g4 * 4;
    int b = g / NANCH;
    int i = g - b * NANCH;          // multiple of 4; level/row boundaries are too
    int lvl, h, s, pos;
    levelOf(i, lvl, h, s, pos);
    int hh = h * h;
    const float* cp = (lvl == 0) ? c0 : (lvl == 1) ? c1 : (lvl == 2) ? c2 : (lvl == 3) ? c3 : c4;
    const float* base = cp + (size_t)b * NCLS * hh + pos;
    float4 mx = make_float4(-1e30f, -1e30f, -1e30f, -1e30f);
    #pragma unroll
    for (int c = 0; c < NCLS; ++c) {
        float4 v = *(const float4*)(base + (size_t)c * hh);
        mx.x = fmaxf(mx.x, v.x); mx.y = fmaxf(mx.y, v.y);
        mx.z = fmaxf(mx.z, v.z); mx.w = fmaxf(mx.w, v.w);
    }
    float4 sc = make_float4(sigmoidf(mx.x), sigmoidf(mx.y), sigmoidf(mx.z), sigmoidf(mx.w));
    *(float4*)(scores + g) = sc;
    unsigned int* hb = hist + (size_t)b * NBIN;
    atomicAdd(&hb[__float_as_uint(sc.x) >> BSHIFT], 1u);
    atomicAdd(&hb[__float_as_uint(sc.y) >> BSHIFT], 1u);
    atomicAdd(&hb[__float_as_uint(sc.z) >> BSHIFT], 1u);
    atomicAdd(&hb[__float_as_uint(sc.w) >> BSHIFT], 1u);
}

// ---- Kernel 2a: find threshold bin per batch (K-th largest), parallel scan ------
__global__ __launch_bounds__(256) void k_findT(
    const unsigned int* __restrict__ hist, int* __restrict__ tbin)
{
    int b = blockIdx.x;
    int tid = threadIdx.x;
    const unsigned int* hb = hist + (size_t)b * NBIN;
    __shared__ unsigned int sc[256];
    __shared__ unsigned int fsc[128];
    __shared__ int s_c, s_t;

    // chunk sums: thread t owns contiguous bins [t*128, t*128+128)
    unsigned int s = 0;
    const uint4* hv = (const uint4*)(hb + (size_t)tid * 128);
    #pragma unroll 8
    for (int k = 0; k < 32; ++k) {
        uint4 v = hv[k];
        s += v.x + v.y + v.z + v.w;
    }
    sc[tid] = s;
    if (tid == 0) { s_c = 0; s_t = 0; }
    __syncthreads();
    // inclusive suffix scan over 256 chunk sums
    for (int d = 1; d < 256; d <<= 1) {
        unsigned int add = (tid + d < 256) ? sc[tid + d] : 0;
        __syncthreads();
        sc[tid] += add;
        __syncthreads();
    }
    // largest chunk c with suffix >= KTOP (unique)
    if (sc[tid] >= (unsigned int)KTOP && (tid == 255 || sc[tid + 1] < (unsigned int)KTOP))
        s_c = tid;
    __syncthreads();
    int c = s_c;
    unsigned int hi = (c < 255) ? sc[c + 1] : 0;
    // stage chunk c's 128 bins, suffix scan
    if (tid < 128) fsc[tid] = hb[c * 128 + tid];
    __syncthreads();
    for (int d = 1; d < 128; d <<= 1) {
        unsigned int add = (tid < 128 && tid + d < 128) ? fsc[tid + d] : 0;
        __syncthreads();
        if (tid < 128) fsc[tid] += add;
        __syncthreads();
    }
    if (tid < 128 && hi + fsc[tid] >= (unsigned int)KTOP &&
        (tid == 127 || hi + fsc[tid + 1] < (unsigned int)KTOP))
        s_t = tid;
    __syncthreads();
    if (tid == 0) tbin[b] = c * 128 + s_t;
}

// ---- Kernel 2b: compact candidates (bin >= threshold bin) -----------------------
__global__ __launch_bounds__(256) void k_compact(
    const float* __restrict__ scores, const int* __restrict__ tbin,
    int* __restrict__ cnt, unsigned long long* __restrict__ cand)
{
    int b = blockIdx.y;
    int i = blockIdx.x * 256 + threadIdx.x;
    if (i >= NANCH) return;
    unsigned int bits = __float_as_uint(scores[(size_t)b * NANCH + i]);
    if ((int)(bits >> BSHIFT) >= tbin[b]) {
        int pos = atomicAdd(&cnt[b], 1);
        if (pos < CAND)
            cand[(size_t)b * CAND + pos] =
                ((unsigned long long)bits << 32) |
                (unsigned long long)(0xFFFFFFFFu - (unsigned int)i);
    }
}

// ---- Kernel 2c: per-batch bitonic sort of candidates, emit exact top-K ----------
__global__ __launch_bounds__(1024) void k_sortk(
    const unsigned long long* __restrict__ cand, const int* __restrict__ cnt,
    float* __restrict__ tsc, int* __restrict__ tix)
{
    int b = blockIdx.x;
    int tid = threadIdx.x;
    __shared__ unsigned long long keys[CAND];
    int n = cnt[b]; if (n > CAND) n = CAND;
    for (int i = tid; i < CAND; i += 1024)
        keys[i] = (i < n) ? cand[(size_t)b * CAND + i] : 0ull;
    __syncthreads();
    for (int sz = 2; sz <= CAND; sz <<= 1) {
        for (int st = sz >> 1; st > 0; st >>= 1) {
            for (int i = tid; i < CAND; i += 1024) {
                int j = i ^ st;
                if (j > i) {
                    unsigned long long a = keys[i], c = keys[j];
                    bool desc = ((i & sz) == 0);
                    if (desc ? (a < c) : (a > c)) { keys[i] = c; keys[j] = a; }
                }
            }
            __syncthreads();
        }
    }
    if (tid < KTOP) {
        unsigned long long key = keys[tid];
        tsc[b * KTOP + tid] = __uint_as_float((unsigned int)(key >> 32));
        tix[b * KTOP + tid] = (int)(0xFFFFFFFFu - (unsigned int)(key & 0xFFFFFFFFull));
    }
}

// ---- Kernel 3: decode boxes + exact class argmax for selected anchors -----------
__global__ __launch_bounds__(256) void k_decode(
    const float* __restrict__ c0, const float* __restrict__ c1,
    const float* __restrict__ c2, const float* __restrict__ c3,
    const float* __restrict__ c4,
    const float* __restrict__ r0, const float* __restrict__ r1,
    const float* __restrict__ r2, const float* __restrict__ r3,
    const float* __restrict__ r4,
    const float* __restrict__ t0, const float* __restrict__ t1,
    const float* __restrict__ t2, const float* __restrict__ t3,
    const float* __restrict__ t4,
    const float* __restrict__ q0, const float* __restrict__ q1,
    const float* __restrict__ q2, const float* __restrict__ q3,
    const float* __restrict__ q4,
    const int* __restrict__ tix, float* __restrict__ boxes, int* __restrict__ clstop)
{
    int g = blockIdx.x * 256 + threadIdx.x;
    if (g >= BATCH * KTOP) return;
    int b = g / KTOP;
    int idx = tix[g];
    int lvl, h, s, pos;
    levelOf(idx, lvl, h, s, pos);
    int y = pos / h, x = pos - y * h;
    int hh = h * h;
    const float* cp = (lvl == 0) ? c0 : (lvl == 1) ? c1 : (lvl == 2) ? c2 : (lvl == 3) ? c3 : c4;
    const float* rp = (lvl == 0) ? r0 : (lvl == 1) ? r1 : (lvl == 2) ? r2 : (lvl == 3) ? r3 : r4;
    const float* tp = (lvl == 0) ? t0 : (lvl == 1) ? t1 : (lvl == 2) ? t2 : (lvl == 3) ? t3 : t4;
    const float* qp = (lvl == 0) ? q0 : (lvl == 1) ? q1 : (lvl == 2) ? q2 : (lvl == 3) ? q3 : q4;
    int off = y * h + x;

    // exact class argmax over sigmoids (first-index tie-break, matches jnp.argmax)
    const float* cb = cp + (size_t)b * NCLS * hh + off;
    float bestc = -1e30f; int bc = 0;
    #pragma unroll
    for (int c = 0; c < NCLS; ++c) {
        float v = sigmoidf(cb[(size_t)c * hh]);
        if (v > bestc) { bestc = v; bc = c; }
    }
    clstop[g] = bc + 1;

    // theta-class argmax over sigmoids (first-index tie-break)
    const float* tb = tp + (size_t)b * NTH * hh + off;
    float best = -1e30f; int bt = 0;
    #pragma unroll
    for (int c = 0; c < NTH; ++c) {
        float v = sigmoidf(tb[(size_t)c * hh]);
        if (v > best) { best = v; bt = c; }
    }
    float theta = (float)(bt + 1) * 10.0f + qp[(size_t)b * hh + off];

    const float* rb = rp + (size_t)b * 5 * hh + off;
    float fs = (float)s;
    float rr0 = rb[0] * fs;
    float rr1 = rb[(size_t)hh] * fs;
    float rr2 = rb[(size_t)2 * hh] * fs;
    float rr3 = rb[(size_t)3 * hh] * fs;
    float cx = (float)(x * s + (s >> 1));
    float cy = (float)(y * s + (s >> 1));
    float* op = boxes + (size_t)g * 5;
    op[0] = cx - rr0;
    op[1] = cy - rr1;
    op[2] = cx + rr2;
    op[3] = cy + rr3;
    op[4] = theta;
}

// ---- Kernel 4a: suppression bitmask, word-major [b][w][1024] ---------------------
// one thread per (row i, word w); wave = 64 consecutive i, same w
__global__ __launch_bounds__(256) void k_mask(
    const float* __restrict__ boxes, unsigned long long* __restrict__ mask)
{
    int b = blockIdx.x;
    int i_tile = blockIdx.y >> 2;      // 0..15 (64 rows each)
    int w_tile = blockIdx.y & 3;       // 0..3  (4 words each)
    __shared__ float bx1[KTOP], by1[KTOP], bx2[KTOP], by2[KTOP], bar[KTOP];
    for (int r = threadIdx.x; r < KTOP; r += 256) {
        const float* p = boxes + ((size_t)(b * KTOP + r)) * 5;
        float x1 = p[0], y1 = p[1], x2 = p[2], y2 = p[3];
        bx1[r] = x1; by1[r] = y1; bx2[r] = x2; by2[r] = y2;
        bar[r] = fmaxf(x2 - x1, 0.0f) * fmaxf(y2 - y1, 0.0f);
    }
    __syncthreads();
    int i = (i_tile << 6) + (threadIdx.x & 63);
    int w = (w_tile << 2) + (threadIdx.x >> 6);
    if (i >= KTOP) return;
    int j0 = w << 6;
    int lo = (j0 > i + 1) ? j0 : (i + 1);
    int hi = (j0 + 64 < KTOP) ? (j0 + 64) : KTOP;
    unsigned long long m = 0ull;
    if (lo < hi) {
        float x1 = bx1[i], y1 = by1[i], x2 = bx2[i], y2 = by2[i], ai = bar[i];
        for (int j = lo; j < hi; ++j) {
            float iw = fminf(x2, bx2[j]) - fmaxf(x1, bx1[j]);
            iw = fmaxf(iw, 0.0f);
            float ih = fminf(y2, by2[j]) - fmaxf(y1, by1[j]);
            ih = fmaxf(ih, 0.0f);
            float inter = iw * ih;
            float u = ai + bar[j] - inter;
            float iou = inter / fmaxf(u, 1e-8f);
            if (iou > 0.3f) m |= (1ull << (j - j0));
        }
    }
    mask[((size_t)(b * NWORDS + w)) * 1024 + i] = m;   // lane-coalesced
}

// ---- Kernel 4b: greedy sequential NMS (one wave per batch) ----------------------
__global__ __launch_bounds__(64) void k_nms(
    const unsigned long long* __restrict__ mask,
    const float* __restrict__ tsc, int* __restrict__ keep)
{
    int b = blockIdx.x;
    int l = threadIdx.x;
    __shared__ unsigned long long sremv[NWORDS];
    __shared__ unsigned long long skeep[NWORDS];
    __shared__ unsigned long long svalid[NWORDS];

    if (l < NWORDS) sremv[l] = 0ull;
    for (int w = 0; w < NWORDS; ++w) {
        int i = (w << 6) + l;
        bool v = (i < KTOP) && (tsc[b * KTOP + i] >= 0.05f);
        unsigned long long bm = __ballot(v);
        if (l == 0) svalid[w] = bm;
    }
    __syncthreads();

    for (int w = 0; w < NWORDS; ++w) {
        int base = w << 6;
        int nrow = (KTOP - base < 64) ? (KTOP - base) : 64;
        unsigned long long rowword = 0ull;
        if (l < nrow)
            rowword = mask[((size_t)(b * NWORDS + w)) * 1024 + base + l];
        unsigned long long remw = sremv[w];
        unsigned long long validw = svalid[w];
        unsigned long long keptm = 0ull;
        for (int jj = 0; jj < nrow; ++jj) {
            if (((validw >> jj) & 1ull) && !((remw >> jj) & 1ull)) {
                keptm |= (1ull << jj);
                remw |= shfl_u64(rowword, jj);
            }
        }
        if (l == 0) skeep[w] = keptm;

        int w2 = w + 1 + (int)(l & 15);
        unsigned long long part = 0ull;
        if (w2 < NWORDS) {
            for (int jj = (l >> 4); jj < nrow; jj += 4) {
                if ((keptm >> jj) & 1ull)
                    part |= mask[((size_t)(b * NWORDS + w2)) * 1024 + base + jj];
            }
        }
        part |= shflxor_u64(part, 16);
        part |= shflxor_u64(part, 32);
        if (w2 < NWORDS && (l >> 4) == 0 && part)
            atomicOr64Shared(&sremv[w2], part);
        __syncthreads();
    }

    for (int i = l; i < KTOP; i += 64) {
        keep[b * KTOP + i] = (int)((skeep[i >> 6] >> (i & 63)) & 1ull);
    }
}

// ---- Kernel 5: masked output write -----------------------------------------------
__global__ __launch_bounds__(256) void k_out(
    const float* __restrict__ tsc, const int* __restrict__ clstop,
    const float* __restrict__ boxes,
    const int* __restrict__ keep, float* __restrict__ out)
{
    int g = blockIdx.x * 256 + threadIdx.x;
    if (g >= BATCH * KTOP) return;
    int k = keep[g];
    float fk = (float)k;
    out[g] = tsc[g] * fk;
    out[BATCH * KTOP + g] = (float)(clstop[g] * k);
    const float* bp = boxes + (size_t)g * 5;
    float* op = out + 2 * BATCH * KTOP + (size_t)g * 5;
    op[0] = bp[0] * fk;
    op[1] = bp[1] * fk;
    op[2] = bp[2] * fk;
    op[3] = bp[3] * fk;
    op[4] = bp[4] * fk;
}

extern "C" void kernel_launch(void* const* d_in, const int* in_sizes, int n_in,
                              void* d_out, int out_size, void* d_ws, size_t ws_size,
                              hipStream_t stream) {
    const float* c0 = (const float*)d_in[0];
    const float* c1 = (const float*)d_in[1];
    const float* c2 = (const float*)d_in[2];
    const float* c3 = (const float*)d_in[3];
    const float* c4 = (const float*)d_in[4];
    const float* r0 = (const float*)d_in[5];
    const float* r1 = (const float*)d_in[6];
    const float* r2 = (const float*)d_in[7];
    const float* r3 = (const float*)d_in[8];
    const float* r4 = (const float*)d_in[9];
    const float* t0 = (const float*)d_in[10];
    const float* t1 = (const float*)d_in[11];
    const float* t2 = (const float*)d_in[12];
    const float* t3 = (const float*)d_in[13];
    const float* t4 = (const float*)d_in[14];
    const float* q0 = (const float*)d_in[15];
    const float* q1 = (const float*)d_in[16];
    const float* q2 = (const float*)d_in[17];
    const float* q3 = (const float*)d_in[18];
    const float* q4 = (const float*)d_in[19];

    // Workspace layout, total 5,815,936 B. Aliases are safe by stream order:
    //   hist (k_scores→k_findT) aliases mask (k_mask→k_nms)   [findT before mask]
    //   cand (k_compact→k_sortk) aliases boxes (k_decode→...) [sortk before decode]
    char* ws = (char*)d_ws;
    float*              scores  = (float*)(ws + 0);          // 3,142,656
    float*              tsc     = (float*)(ws + 3142656);    //    64,000
    int*                tix     = (int*)(ws + 3206656);      //    64,000
    float*              boxes   = (float*)(ws + 3270656);    //   320,000
    unsigned long long* cand    = (unsigned long long*)(ws + 3270656); // 262,144 alias
    int*                clstop  = (int*)(ws + 3590656);      //    64,000
    unsigned long long* mask    = (unsigned long long*)(ws + 3654656); // 2,097,152
    unsigned int*       hist    = (unsigned int*)(ws + 3654656);       // 2,097,152 alias
    int*                keep    = (int*)(ws + 5751808);      //    64,000
    int*                tcnt    = (int*)(ws + 5815808);      //        64
    int*                tbin    = (int*)(ws + 5815872);      //        64
    float*              out     = (float*)d_out;

    // zero hist..tcnt (covers keep too — harmless, it's rewritten before use)
    hipMemsetAsync(ws + 3654656, 0, 2161216, stream);

    k_scores<<<(BATCH * NANCH / 4 + 255) / 256, 256, 0, stream>>>(
        c0, c1, c2, c3, c4, scores, hist);
    k_findT<<<BATCH, 256, 0, stream>>>(hist, tbin);
    k_compact<<<dim3((NANCH + 255) / 256, BATCH), 256, 0, stream>>>(scores, tbin, tcnt, cand);
    k_sortk<<<BATCH, 1024, 0, stream>>>(cand, tcnt, tsc, tix);
    k_decode<<<(BATCH * KTOP + 255) / 256, 256, 0, stream>>>(
        c0, c1, c2, c3, c4,
        r0, r1, r2, r3, r4, t0, t1, t2, t3, t4, q0, q1, q2, q3, q4,
        tix, boxes, clstop);
    k_mask<<<dim3(BATCH, 64), 256, 0, stream>>>(boxes, mask);
    k_nms<<<BATCH, 64, 0, stream>>>(mask, tsc, keep);
    k_out<<<(BATCH * KTOP + 255) / 256, 256, 0, stream>>>(tsc, clstop, boxes, keep, out);
}

// Round 4
// 344.124 us; speedup vs baseline: 1.5143x; 1.1870x over previous
//
#include <hip/hip_runtime.h>
#include <stdint.h>

#define NCLS   15
#define NTH    18
#define BATCH  16
#define NANCH  49104
#define KTOP   1000
#define NWORDS 16   // 16*64 = 1024 >= 1000
#define NBIN   32768
#define BSHIFT 15
#define CAND   2048

__device__ __forceinline__ float sigmoidf(float x) {
    return 1.0f / (1.0f + expf(-x));
}

__device__ __forceinline__ void levelOf(int i, int& lvl, int& h, int& s, int& pos) {
    if (i < 36864)      { lvl = 0; h = 192; s = 8;   pos = i; }
    else if (i < 46080) { lvl = 1; h = 96;  s = 16;  pos = i - 36864; }
    else if (i < 48384) { lvl = 2; h = 48;  s = 32;  pos = i - 46080; }
    else if (i < 48960) { lvl = 3; h = 24;  s = 64;  pos = i - 48384; }
    else                { lvl = 4; h = 12;  s = 128; pos = i - 48960; }
}

__device__ __forceinline__ unsigned long long shflxor_u64(unsigned long long v, int m) {
    int lo = __shfl_xor((int)(unsigned int)(v & 0xFFFFFFFFull), m);
    int hi = __shfl_xor((int)(unsigned int)(v >> 32), m);
    return ((unsigned long long)(unsigned int)hi << 32) | (unsigned long long)(unsigned int)lo;
}

// ---- Kernel 1: per-anchor score = sigmoid(max logit), float4, + score hist ------
// max_i sigmoid(x_i) == sigmoid(max_i x_i) bitwise (monotone fp composition);
// the tie-sensitive argmax (class id) is computed exactly in k_decode.
__global__ __launch_bounds__(256) void k_scores(
    const float* __restrict__ c0, const float* __restrict__ c1,
    const float* __restrict__ c2, const float* __restrict__ c3,
    const float* __restrict__ c4,
    float* __restrict__ scores, unsigned int* __restrict__ hist)
{
    int g4 = blockIdx.x * 256 + threadIdx.x;
    if (g4 >= BATCH * NANCH / 4) return;
    int g = g4 * 4;
    int b = g / NANCH;
    int i = g - b * NANCH;          // multiple of 4; level/row boundaries are too
    int lvl, h, s, pos;
    levelOf(i, lvl, h, s, pos);
    int hh = h * h;
    const float* cp = (lvl == 0) ? c0 : (lvl == 1) ? c1 : (lvl == 2) ? c2 : (lvl == 3) ? c3 : c4;
    const float* base = cp + (size_t)b * NCLS * hh + pos;
    float4 mx = make_float4(-1e30f, -1e30f, -1e30f, -1e30f);
    #pragma unroll
    for (int c = 0; c < NCLS; ++c) {
        float4 v = *(const float4*)(base + (size_t)c * hh);
        mx.x = fmaxf(mx.x, v.x); mx.y = fmaxf(mx.y, v.y);
        mx.z = fmaxf(mx.z, v.z); mx.w = fmaxf(mx.w, v.w);
    }
    float4 sc = make_float4(sigmoidf(mx.x), sigmoidf(mx.y), sigmoidf(mx.z), sigmoidf(mx.w));
    *(float4*)(scores + g) = sc;
    unsigned int* hb = hist + (size_t)b * NBIN;
    atomicAdd(&hb[__float_as_uint(sc.x) >> BSHIFT], 1u);
    atomicAdd(&hb[__float_as_uint(sc.y) >> BSHIFT], 1u);
    atomicAdd(&hb[__float_as_uint(sc.z) >> BSHIFT], 1u);
    atomicAdd(&hb[__float_as_uint(sc.w) >> BSHIFT], 1u);
}

// ---- Kernel 2a: find threshold bin per batch (K-th largest), parallel scan ------
__global__ __launch_bounds__(256) void k_findT(
    const unsigned int* __restrict__ hist, int* __restrict__ tbin)
{
    int b = blockIdx.x;
    int tid = threadIdx.x;
    const unsigned int* hb = hist + (size_t)b * NBIN;
    __shared__ unsigned int sc[256];
    __shared__ unsigned int fsc[128];
    __shared__ int s_c, s_t;

    unsigned int s = 0;
    const uint4* hv = (const uint4*)(hb + (size_t)tid * 128);
    #pragma unroll 8
    for (int k = 0; k < 32; ++k) {
        uint4 v = hv[k];
        s += v.x + v.y + v.z + v.w;
    }
    sc[tid] = s;
    if (tid == 0) { s_c = 0; s_t = 0; }
    __syncthreads();
    for (int d = 1; d < 256; d <<= 1) {
        unsigned int add = (tid + d < 256) ? sc[tid + d] : 0;
        __syncthreads();
        sc[tid] += add;
        __syncthreads();
    }
    if (sc[tid] >= (unsigned int)KTOP && (tid == 255 || sc[tid + 1] < (unsigned int)KTOP))
        s_c = tid;
    __syncthreads();
    int c = s_c;
    unsigned int hi = (c < 255) ? sc[c + 1] : 0;
    if (tid < 128) fsc[tid] = hb[c * 128 + tid];
    __syncthreads();
    for (int d = 1; d < 128; d <<= 1) {
        unsigned int add = (tid < 128 && tid + d < 128) ? fsc[tid + d] : 0;
        __syncthreads();
        if (tid < 128) fsc[tid] += add;
        __syncthreads();
    }
    if (tid < 128 && hi + fsc[tid] >= (unsigned int)KTOP &&
        (tid == 127 || hi + fsc[tid + 1] < (unsigned int)KTOP))
        s_t = tid;
    __syncthreads();
    if (tid == 0) tbin[b] = c * 128 + s_t;
}

// ---- Kernel 2b: compact candidates (bin >= threshold bin) -----------------------
__global__ __launch_bounds__(256) void k_compact(
    const float* __restrict__ scores, const int* __restrict__ tbin,
    int* __restrict__ cnt, unsigned long long* __restrict__ cand)
{
    int b = blockIdx.y;
    int i = blockIdx.x * 256 + threadIdx.x;
    if (i >= NANCH) return;
    unsigned int bits = __float_as_uint(scores[(size_t)b * NANCH + i]);
    if ((int)(bits >> BSHIFT) >= tbin[b]) {
        int pos = atomicAdd(&cnt[b], 1);
        if (pos < CAND)
            cand[(size_t)b * CAND + pos] =
                ((unsigned long long)bits << 32) |
                (unsigned long long)(0xFFFFFFFFu - (unsigned int)i);
    }
}

// ---- Kernel 2c: per-batch bitonic sort of candidates, emit exact top-K ----------
__global__ __launch_bounds__(1024) void k_sortk(
    const unsigned long long* __restrict__ cand, const int* __restrict__ cnt,
    float* __restrict__ tsc, int* __restrict__ tix)
{
    int b = blockIdx.x;
    int tid = threadIdx.x;
    __shared__ unsigned long long keys[CAND];
    int n = cnt[b]; if (n > CAND) n = CAND;
    for (int i = tid; i < CAND; i += 1024)
        keys[i] = (i < n) ? cand[(size_t)b * CAND + i] : 0ull;
    __syncthreads();
    for (int sz = 2; sz <= CAND; sz <<= 1) {
        for (int st = sz >> 1; st > 0; st >>= 1) {
            for (int i = tid; i < CAND; i += 1024) {
                int j = i ^ st;
                if (j > i) {
                    unsigned long long a = keys[i], c = keys[j];
                    bool desc = ((i & sz) == 0);
                    if (desc ? (a < c) : (a > c)) { keys[i] = c; keys[j] = a; }
                }
            }
            __syncthreads();
        }
    }
    if (tid < KTOP) {
        unsigned long long key = keys[tid];
        tsc[b * KTOP + tid] = __uint_as_float((unsigned int)(key >> 32));
        tix[b * KTOP + tid] = (int)(0xFFFFFFFFu - (unsigned int)(key & 0xFFFFFFFFull));
    }
}

// ---- Kernel 3: decode boxes + exact class argmax for selected anchors -----------
__global__ __launch_bounds__(256) void k_decode(
    const float* __restrict__ c0, const float* __restrict__ c1,
    const float* __restrict__ c2, const float* __restrict__ c3,
    const float* __restrict__ c4,
    const float* __restrict__ r0, const float* __restrict__ r1,
    const float* __restrict__ r2, const float* __restrict__ r3,
    const float* __restrict__ r4,
    const float* __restrict__ t0, const float* __restrict__ t1,
    const float* __restrict__ t2, const float* __restrict__ t3,
    const float* __restrict__ t4,
    const float* __restrict__ q0, const float* __restrict__ q1,
    const float* __restrict__ q2, const float* __restrict__ q3,
    const float* __restrict__ q4,
    const int* __restrict__ tix, float* __restrict__ boxes, int* __restrict__ clstop)
{
    int g = blockIdx.x * 256 + threadIdx.x;
    if (g >= BATCH * KTOP) return;
    int b = g / KTOP;
    int idx = tix[g];
    int lvl, h, s, pos;
    levelOf(idx, lvl, h, s, pos);
    int y = pos / h, x = pos - y * h;
    int hh = h * h;
    const float* cp = (lvl == 0) ? c0 : (lvl == 1) ? c1 : (lvl == 2) ? c2 : (lvl == 3) ? c3 : c4;
    const float* rp = (lvl == 0) ? r0 : (lvl == 1) ? r1 : (lvl == 2) ? r2 : (lvl == 3) ? r3 : r4;
    const float* tp = (lvl == 0) ? t0 : (lvl == 1) ? t1 : (lvl == 2) ? t2 : (lvl == 3) ? t3 : t4;
    const float* qp = (lvl == 0) ? q0 : (lvl == 1) ? q1 : (lvl == 2) ? q2 : (lvl == 3) ? q3 : q4;
    int off = y * h + x;

    const float* cb = cp + (size_t)b * NCLS * hh + off;
    float bestc = -1e30f; int bc = 0;
    #pragma unroll
    for (int c = 0; c < NCLS; ++c) {
        float v = sigmoidf(cb[(size_t)c * hh]);
        if (v > bestc) { bestc = v; bc = c; }
    }
    clstop[g] = bc + 1;

    const float* tb = tp + (size_t)b * NTH * hh + off;
    float best = -1e30f; int bt = 0;
    #pragma unroll
    for (int c = 0; c < NTH; ++c) {
        float v = sigmoidf(tb[(size_t)c * hh]);
        if (v > best) { best = v; bt = c; }
    }
    float theta = (float)(bt + 1) * 10.0f + qp[(size_t)b * hh + off];

    const float* rb = rp + (size_t)b * 5 * hh + off;
    float fs = (float)s;
    float rr0 = rb[0] * fs;
    float rr1 = rb[(size_t)hh] * fs;
    float rr2 = rb[(size_t)2 * hh] * fs;
    float rr3 = rb[(size_t)3 * hh] * fs;
    float cx = (float)(x * s + (s >> 1));
    float cy = (float)(y * s + (s >> 1));
    float* op = boxes + (size_t)g * 5;
    op[0] = cx - rr0;
    op[1] = cy - rr1;
    op[2] = cx + rr2;
    op[3] = cy + rr3;
    op[4] = theta;
}

// ---- Kernel 4a: suppression bitmask, ROW-major [b][1024][16] ---------------------
// thread t: row i = by*16 + (t>>4), word w = t&15 -> block writes 256 contiguous u64
__global__ __launch_bounds__(256) void k_mask(
    const float* __restrict__ boxes, unsigned long long* __restrict__ mask)
{
    int b = blockIdx.x;
    __shared__ float bx1[KTOP], by1[KTOP], bx2[KTOP], by2[KTOP], bar[KTOP];
    for (int r = threadIdx.x; r < KTOP; r += 256) {
        const float* p = boxes + ((size_t)(b * KTOP + r)) * 5;
        float x1 = p[0], y1 = p[1], x2 = p[2], y2 = p[3];
        bx1[r] = x1; by1[r] = y1; bx2[r] = x2; by2[r] = y2;
        bar[r] = fmaxf(x2 - x1, 0.0f) * fmaxf(y2 - y1, 0.0f);
    }
    __syncthreads();
    int i = (blockIdx.y << 4) + (threadIdx.x >> 4);
    int w = threadIdx.x & 15;
    int j0 = w << 6;
    int lo = (j0 > i + 1) ? j0 : (i + 1);
    int hi = (j0 + 64 < KTOP) ? (j0 + 64) : KTOP;
    unsigned long long m = 0ull;
    if (i < KTOP && lo < hi) {
        float x1 = bx1[i], y1 = by1[i], x2 = bx2[i], y2 = by2[i], ai = bar[i];
        for (int j = lo; j < hi; ++j) {
            float iw = fminf(x2, bx2[j]) - fmaxf(x1, bx1[j]);
            iw = fmaxf(iw, 0.0f);
            float ih = fminf(y2, by2[j]) - fmaxf(y1, by1[j]);
            ih = fmaxf(ih, 0.0f);
            float inter = iw * ih;
            float u = ai + bar[j] - inter;
            float iou = inter / fmaxf(u, 1e-8f);
            if (iou > 0.3f) m |= (1ull << (j - j0));
        }
    }
    mask[(((size_t)b * 1024 + i) << 4) + w] = m;
}

// ---- Kernel 4b: greedy NMS, one wave per batch, register-chain + fused output ---
__global__ __launch_bounds__(64) void k_nms(
    const unsigned long long* __restrict__ mask,   // [b][1024][16]
    const float* __restrict__ tsc, const int* __restrict__ clstop,
    const float* __restrict__ boxes, float* __restrict__ out)
{
    const int b = blockIdx.x;
    const int l = threadIdx.x;
    __shared__ unsigned long long sdiag[64];

    // per-phase valid words (ballot -> uniform)
    unsigned long long vw[NWORDS];
    #pragma unroll
    for (int w = 0; w < NWORDS; ++w) {
        int i = (w << 6) + l;
        bool v = (i < KTOP) && (tsc[b * KTOP + i] >= 0.05f);
        vw[w] = __ballot(v);
    }

    unsigned long long part[NWORDS];
    #pragma unroll
    for (int w = 0; w < NWORDS; ++w) part[w] = 0ull;

    unsigned long long keepw[NWORDS];

    #pragma unroll
    for (int w = 0; w < NWORDS; ++w) {
        const int base = w << 6;
        // lane l owns row base+l; load its words w..15 (contiguous, 16B vectors)
        const unsigned long long* rp = mask + (((size_t)b * 1024 + base + l) << 4);
        unsigned long long row[NWORDS];
        #pragma unroll
        for (int p = (w >> 1); p < 8; ++p) {
            ulonglong2 v = *(const ulonglong2*)(rp + (p << 1));
            row[p * 2] = v.x; row[p * 2 + 1] = v.y;
        }
        sdiag[l] = row[w];
        __syncthreads();

        // rem word for this phase: butterfly-OR of per-lane partials
        unsigned long long remw = part[w];
        remw |= shflxor_u64(remw, 1);
        remw |= shflxor_u64(remw, 2);
        remw |= shflxor_u64(remw, 4);
        remw |= shflxor_u64(remw, 8);
        remw |= shflxor_u64(remw, 16);
        remw |= shflxor_u64(remw, 32);

        // uniform branchless greedy over the 64 in-word boxes;
        // chain = pure VALU, sdiag reads have static addresses (prefetchable)
        unsigned long long keptm = 0ull;
        unsigned long long valid = vw[w];
        #pragma unroll 8
        for (int jj = 0; jj < 64; ++jj) {
            unsigned long long take = ((valid & ~remw) >> jj) & 1ull;
            keptm |= take << jj;
            remw |= sdiag[jj] & (0ull - take);
        }
        keepw[w] = keptm;

        // lane-local: kept rows OR their future words into this lane's partials
        unsigned long long sel = 0ull - ((keptm >> l) & 1ull);
        #pragma unroll
        for (int w2 = w + 1; w2 < NWORDS; ++w2)
            part[w2] |= row[w2] & sel;
        __syncthreads();
    }

    // fused masked output write
    #pragma unroll
    for (int w = 0; w < NWORDS; ++w) {
        int i = (w << 6) + l;
        if (i < KTOP) {
            int g = b * KTOP + i;
            float fk = (float)((keepw[w] >> l) & 1ull);
            out[g] = tsc[g] * fk;
            out[BATCH * KTOP + g] = (float)clstop[g] * fk;
            const float* bp = boxes + (size_t)g * 5;
            float* op = out + 2 * BATCH * KTOP + (size_t)g * 5;
            op[0] = bp[0] * fk;
            op[1] = bp[1] * fk;
            op[2] = bp[2] * fk;
            op[3] = bp[3] * fk;
            op[4] = bp[4] * fk;
        }
    }
}

extern "C" void kernel_launch(void* const* d_in, const int* in_sizes, int n_in,
                              void* d_out, int out_size, void* d_ws, size_t ws_size,
                              hipStream_t stream) {
    const float* c0 = (const float*)d_in[0];
    const float* c1 = (const float*)d_in[1];
    const float* c2 = (const float*)d_in[2];
    const float* c3 = (const float*)d_in[3];
    const float* c4 = (const float*)d_in[4];
    const float* r0 = (const float*)d_in[5];
    const float* r1 = (const float*)d_in[6];
    const float* r2 = (const float*)d_in[7];
    const float* r3 = (const float*)d_in[8];
    const float* r4 = (const float*)d_in[9];
    const float* t0 = (const float*)d_in[10];
    const float* t1 = (const float*)d_in[11];
    const float* t2 = (const float*)d_in[12];
    const float* t3 = (const float*)d_in[13];
    const float* t4 = (const float*)d_in[14];
    const float* q0 = (const float*)d_in[15];
    const float* q1 = (const float*)d_in[16];
    const float* q2 = (const float*)d_in[17];
    const float* q3 = (const float*)d_in[18];
    const float* q4 = (const float*)d_in[19];

    // Workspace layout, total 5,815,936 B. Aliases safe by stream order:
    //   hist (k_scores→k_findT) aliases mask (k_mask→k_nms)   [findT before mask]
    //   cand (k_compact→k_sortk) aliases boxes (k_decode→...) [sortk before decode]
    char* ws = (char*)d_ws;
    float*              scores  = (float*)(ws + 0);          // 3,142,656
    float*              tsc     = (float*)(ws + 3142656);    //    64,000
    int*                tix     = (int*)(ws + 3206656);      //    64,000
    float*              boxes   = (float*)(ws + 3270656);    //   320,000
    unsigned long long* cand    = (unsigned long long*)(ws + 3270656); // 262,144 alias
    int*                clstop  = (int*)(ws + 3590656);      //    64,000
    unsigned long long* mask    = (unsigned long long*)(ws + 3654656); // 2,097,152
    unsigned int*       hist    = (unsigned int*)(ws + 3654656);       // alias
    int*                tcnt    = (int*)(ws + 5815808);      //        64
    int*                tbin    = (int*)(ws + 5815872);      //        64
    float*              out     = (float*)d_out;

    // zero hist + tcnt
    hipMemsetAsync(ws + 3654656, 0, 2161216, stream);

    k_scores<<<(BATCH * NANCH / 4 + 255) / 256, 256, 0, stream>>>(
        c0, c1, c2, c3, c4, scores, hist);
    k_findT<<<BATCH, 256, 0, stream>>>(hist, tbin);
    k_compact<<<dim3((NANCH + 255) / 256, BATCH), 256, 0, stream>>>(scores, tbin, tcnt, cand);
    k_sortk<<<BATCH, 1024, 0, stream>>>(cand, tcnt, tsc, tix);
    k_decode<<<(BATCH * KTOP + 255) / 256, 256, 0, stream>>>(
        c0, c1, c2, c3, c4,
        r0, r1, r2, r3, r4, t0, t1, t2, t3, t4, q0, q1, q2, q3, q4,
        tix, boxes, clstop);
    k_mask<<<dim3(BATCH, 64), 256, 0, stream>>>(boxes, mask);
    k_nms<<<BATCH, 64, 0, stream>>>(mask, tsc, clstop, boxes, out);
}

// Round 5
// 236.291 us; speedup vs baseline: 2.2053x; 1.4564x over previous
//
#include <hip/hip_runtime.h>
#include <stdint.h>

#define NCLS   15
#define NTH    18
#define BATCH  16
#define NANCH  49104
#define KTOP   1000
#define NWORDS 16   // 16*64 = 1024 >= 1000
#define NBIN   32768
#define BSHIFT 15
#define CAND   2048

__device__ __forceinline__ float sigmoidf(float x) {
    return 1.0f / (1.0f + expf(-x));
}

__device__ __forceinline__ void levelOf(int i, int& lvl, int& h, int& s, int& pos) {
    if (i < 36864)      { lvl = 0; h = 192; s = 8;   pos = i; }
    else if (i < 46080) { lvl = 1; h = 96;  s = 16;  pos = i - 36864; }
    else if (i < 48384) { lvl = 2; h = 48;  s = 32;  pos = i - 46080; }
    else if (i < 48960) { lvl = 3; h = 24;  s = 64;  pos = i - 48384; }
    else                { lvl = 4; h = 12;  s = 128; pos = i - 48960; }
}

__device__ __forceinline__ unsigned long long shflxor_u64(unsigned long long v, int m) {
    int lo = __shfl_xor((int)(unsigned int)(v & 0xFFFFFFFFull), m);
    int hi = __shfl_xor((int)(unsigned int)(v >> 32), m);
    return ((unsigned long long)(unsigned int)hi << 32) | (unsigned long long)(unsigned int)lo;
}

// ---- Kernel 1: per-anchor score = sigmoid(max logit), float4, + score hist ------
__global__ __launch_bounds__(256) void k_scores(
    const float* __restrict__ c0, const float* __restrict__ c1,
    const float* __restrict__ c2, const float* __restrict__ c3,
    const float* __restrict__ c4,
    float* __restrict__ scores, unsigned int* __restrict__ hist)
{
    int g4 = blockIdx.x * 256 + threadIdx.x;
    if (g4 >= BATCH * NANCH / 4) return;
    int g = g4 * 4;
    int b = g / NANCH;
    int i = g - b * NANCH;
    int lvl, h, s, pos;
    levelOf(i, lvl, h, s, pos);
    int hh = h * h;
    const float* cp = (lvl == 0) ? c0 : (lvl == 1) ? c1 : (lvl == 2) ? c2 : (lvl == 3) ? c3 : c4;
    const float* base = cp + (size_t)b * NCLS * hh + pos;
    float4 mx = make_float4(-1e30f, -1e30f, -1e30f, -1e30f);
    #pragma unroll
    for (int c = 0; c < NCLS; ++c) {
        float4 v = *(const float4*)(base + (size_t)c * hh);
        mx.x = fmaxf(mx.x, v.x); mx.y = fmaxf(mx.y, v.y);
        mx.z = fmaxf(mx.z, v.z); mx.w = fmaxf(mx.w, v.w);
    }
    float4 sc = make_float4(sigmoidf(mx.x), sigmoidf(mx.y), sigmoidf(mx.z), sigmoidf(mx.w));
    *(float4*)(scores + g) = sc;
    unsigned int* hb = hist + (size_t)b * NBIN;
    atomicAdd(&hb[__float_as_uint(sc.x) >> BSHIFT], 1u);
    atomicAdd(&hb[__float_as_uint(sc.y) >> BSHIFT], 1u);
    atomicAdd(&hb[__float_as_uint(sc.z) >> BSHIFT], 1u);
    atomicAdd(&hb[__float_as_uint(sc.w) >> BSHIFT], 1u);
}

// ---- Kernel 2a: find threshold bin per batch (K-th largest), parallel scan ------
__global__ __launch_bounds__(256) void k_findT(
    const unsigned int* __restrict__ hist, int* __restrict__ tbin)
{
    int b = blockIdx.x;
    int tid = threadIdx.x;
    const unsigned int* hb = hist + (size_t)b * NBIN;
    __shared__ unsigned int sc[256];
    __shared__ unsigned int fsc[128];
    __shared__ int s_c, s_t;

    unsigned int s = 0;
    const uint4* hv = (const uint4*)(hb + (size_t)tid * 128);
    #pragma unroll 8
    for (int k = 0; k < 32; ++k) {
        uint4 v = hv[k];
        s += v.x + v.y + v.z + v.w;
    }
    sc[tid] = s;
    if (tid == 0) { s_c = 0; s_t = 0; }
    __syncthreads();
    for (int d = 1; d < 256; d <<= 1) {
        unsigned int add = (tid + d < 256) ? sc[tid + d] : 0;
        __syncthreads();
        sc[tid] += add;
        __syncthreads();
    }
    if (sc[tid] >= (unsigned int)KTOP && (tid == 255 || sc[tid + 1] < (unsigned int)KTOP))
        s_c = tid;
    __syncthreads();
    int c = s_c;
    unsigned int hi = (c < 255) ? sc[c + 1] : 0;
    if (tid < 128) fsc[tid] = hb[c * 128 + tid];
    __syncthreads();
    for (int d = 1; d < 128; d <<= 1) {
        unsigned int add = (tid < 128 && tid + d < 128) ? fsc[tid + d] : 0;
        __syncthreads();
        if (tid < 128) fsc[tid] += add;
        __syncthreads();
    }
    if (tid < 128 && hi + fsc[tid] >= (unsigned int)KTOP &&
        (tid == 127 || hi + fsc[tid + 1] < (unsigned int)KTOP))
        s_t = tid;
    __syncthreads();
    if (tid == 0) tbin[b] = c * 128 + s_t;
}

// ---- Kernel 2b: compact candidates — block-aggregated, padded counters ----------
// grid (48, BATCH); block = 256 threads x 4 anchors (float4). One LDS rank-count
// per block, ONE global atomic per block (cnt stride 64 B -> no line sharing).
__global__ __launch_bounds__(256) void k_compact(
    const float* __restrict__ scores, const int* __restrict__ tbin,
    int* __restrict__ cnt, unsigned long long* __restrict__ cand)
{
    const int b = blockIdx.y;
    const int t4 = blockIdx.x * 256 + threadIdx.x;   // float4 index within batch
    __shared__ int lcnt;
    __shared__ int lbase;
    if (threadIdx.x == 0) lcnt = 0;
    __syncthreads();

    const int T = tbin[b];
    const bool in = (t4 < NANCH / 4);
    float4 v = make_float4(0.f, 0.f, 0.f, 0.f);
    if (in) v = *(const float4*)(scores + (size_t)b * NANCH + 4 * (size_t)t4);
    unsigned int bits[4] = { __float_as_uint(v.x), __float_as_uint(v.y),
                             __float_as_uint(v.z), __float_as_uint(v.w) };
    int rank[4];
    #pragma unroll
    for (int k = 0; k < 4; ++k) {
        bool pass = in && ((int)(bits[k] >> BSHIFT) >= T);
        rank[k] = pass ? atomicAdd(&lcnt, 1) : -1;
    }
    __syncthreads();
    if (threadIdx.x == 0) lbase = atomicAdd(&cnt[b * 16], lcnt);
    __syncthreads();
    const int base = lbase;
    #pragma unroll
    for (int k = 0; k < 4; ++k) {
        if (rank[k] >= 0) {
            int p = base + rank[k];
            if (p < CAND) {
                unsigned int idx = 4u * (unsigned int)t4 + (unsigned int)k;
                cand[(size_t)b * CAND + p] =
                    ((unsigned long long)bits[k] << 32) |
                    (unsigned long long)(0xFFFFFFFFu - idx);
            }
        }
    }
}

// ---- Kernel 2c: per-batch bitonic sort of candidates, emit exact top-K ----------
__global__ __launch_bounds__(1024) void k_sortk(
    const unsigned long long* __restrict__ cand, const int* __restrict__ cnt,
    float* __restrict__ tsc, int* __restrict__ tix)
{
    int b = blockIdx.x;
    int tid = threadIdx.x;
    __shared__ unsigned long long keys[CAND];
    int n = cnt[b * 16]; if (n > CAND) n = CAND;
    for (int i = tid; i < CAND; i += 1024)
        keys[i] = (i < n) ? cand[(size_t)b * CAND + i] : 0ull;
    __syncthreads();
    for (int sz = 2; sz <= CAND; sz <<= 1) {
        for (int st = sz >> 1; st > 0; st >>= 1) {
            for (int i = tid; i < CAND; i += 1024) {
                int j = i ^ st;
                if (j > i) {
                    unsigned long long a = keys[i], c = keys[j];
                    bool desc = ((i & sz) == 0);
                    if (desc ? (a < c) : (a > c)) { keys[i] = c; keys[j] = a; }
                }
            }
            __syncthreads();
        }
    }
    if (tid < KTOP) {
        unsigned long long key = keys[tid];
        tsc[b * KTOP + tid] = __uint_as_float((unsigned int)(key >> 32));
        tix[b * KTOP + tid] = (int)(0xFFFFFFFFu - (unsigned int)(key & 0xFFFFFFFFull));
    }
}

// ---- Kernel 3: decode boxes + exact class argmax for selected anchors -----------
__global__ __launch_bounds__(256) void k_decode(
    const float* __restrict__ c0, const float* __restrict__ c1,
    const float* __restrict__ c2, const float* __restrict__ c3,
    const float* __restrict__ c4,
    const float* __restrict__ r0, const float* __restrict__ r1,
    const float* __restrict__ r2, const float* __restrict__ r3,
    const float* __restrict__ r4,
    const float* __restrict__ t0, const float* __restrict__ t1,
    const float* __restrict__ t2, const float* __restrict__ t3,
    const float* __restrict__ t4,
    const float* __restrict__ q0, const float* __restrict__ q1,
    const float* __restrict__ q2, const float* __restrict__ q3,
    const float* __restrict__ q4,
    const int* __restrict__ tix, float* __restrict__ boxes, int* __restrict__ clstop)
{
    int g = blockIdx.x * 256 + threadIdx.x;
    if (g >= BATCH * KTOP) return;
    int b = g / KTOP;
    int idx = tix[g];
    int lvl, h, s, pos;
    levelOf(idx, lvl, h, s, pos);
    int y = pos / h, x = pos - y * h;
    int hh = h * h;
    const float* cp = (lvl == 0) ? c0 : (lvl == 1) ? c1 : (lvl == 2) ? c2 : (lvl == 3) ? c3 : c4;
    const float* rp = (lvl == 0) ? r0 : (lvl == 1) ? r1 : (lvl == 2) ? r2 : (lvl == 3) ? r3 : r4;
    const float* tp = (lvl == 0) ? t0 : (lvl == 1) ? t1 : (lvl == 2) ? t2 : (lvl == 3) ? t3 : t4;
    const float* qp = (lvl == 0) ? q0 : (lvl == 1) ? q1 : (lvl == 2) ? q2 : (lvl == 3) ? q3 : q4;
    int off = y * h + x;

    const float* cb = cp + (size_t)b * NCLS * hh + off;
    float bestc = -1e30f; int bc = 0;
    #pragma unroll
    for (int c = 0; c < NCLS; ++c) {
        float v = sigmoidf(cb[(size_t)c * hh]);
        if (v > bestc) { bestc = v; bc = c; }
    }
    clstop[g] = bc + 1;

    const float* tb = tp + (size_t)b * NTH * hh + off;
    float best = -1e30f; int bt = 0;
    #pragma unroll
    for (int c = 0; c < NTH; ++c) {
        float v = sigmoidf(tb[(size_t)c * hh]);
        if (v > best) { best = v; bt = c; }
    }
    float theta = (float)(bt + 1) * 10.0f + qp[(size_t)b * hh + off];

    const float* rb = rp + (size_t)b * 5 * hh + off;
    float fs = (float)s;
    float rr0 = rb[0] * fs;
    float rr1 = rb[(size_t)hh] * fs;
    float rr2 = rb[(size_t)2 * hh] * fs;
    float rr3 = rb[(size_t)3 * hh] * fs;
    float cx = (float)(x * s + (s >> 1));
    float cy = (float)(y * s + (s >> 1));
    float* op = boxes + (size_t)g * 5;
    op[0] = cx - rr0;
    op[1] = cy - rr1;
    op[2] = cx + rr2;
    op[3] = cy + rr3;
    op[4] = theta;
}

// ---- Kernel 4a: suppression bitmask, ROW-major [b][1024][16] ---------------------
__global__ __launch_bounds__(256) void k_mask(
    const float* __restrict__ boxes, unsigned long long* __restrict__ mask)
{
    int b = blockIdx.x;
    __shared__ float bx1[KTOP], by1[KTOP], bx2[KTOP], by2[KTOP], bar[KTOP];
    for (int r = threadIdx.x; r < KTOP; r += 256) {
        const float* p = boxes + ((size_t)(b * KTOP + r)) * 5;
        float x1 = p[0], y1 = p[1], x2 = p[2], y2 = p[3];
        bx1[r] = x1; by1[r] = y1; bx2[r] = x2; by2[r] = y2;
        bar[r] = fmaxf(x2 - x1, 0.0f) * fmaxf(y2 - y1, 0.0f);
    }
    __syncthreads();
    int i = (blockIdx.y << 4) + (threadIdx.x >> 4);
    int w = threadIdx.x & 15;
    int j0 = w << 6;
    int lo = (j0 > i + 1) ? j0 : (i + 1);
    int hi = (j0 + 64 < KTOP) ? (j0 + 64) : KTOP;
    unsigned long long m = 0ull;
    if (i < KTOP && lo < hi) {
        float x1 = bx1[i], y1 = by1[i], x2 = bx2[i], y2 = by2[i], ai = bar[i];
        for (int j = lo; j < hi; ++j) {
            float iw = fminf(x2, bx2[j]) - fmaxf(x1, bx1[j]);
            iw = fmaxf(iw, 0.0f);
            float ih = fminf(y2, by2[j]) - fmaxf(y1, by1[j]);
            ih = fmaxf(ih, 0.0f);
            float inter = iw * ih;
            float u = ai + bar[j] - inter;
            float iou = inter / fmaxf(u, 1e-8f);
            if (iou > 0.3f) m |= (1ull << (j - j0));
        }
    }
    mask[(((size_t)b * 1024 + i) << 4) + w] = m;
}

// ---- Kernel 4b: greedy NMS, one wave per batch, register-chain + fused output ---
__global__ __launch_bounds__(64) void k_nms(
    const unsigned long long* __restrict__ mask,   // [b][1024][16]
    const float* __restrict__ tsc, const int* __restrict__ clstop,
    const float* __restrict__ boxes, float* __restrict__ out)
{
    const int b = blockIdx.x;
    const int l = threadIdx.x;
    __shared__ unsigned long long sdiag[64];

    unsigned long long vw[NWORDS];
    #pragma unroll
    for (int w = 0; w < NWORDS; ++w) {
        int i = (w << 6) + l;
        bool v = (i < KTOP) && (tsc[b * KTOP + i] >= 0.05f);
        vw[w] = __ballot(v);
    }

    unsigned long long part[NWORDS];
    #pragma unroll
    for (int w = 0; w < NWORDS; ++w) part[w] = 0ull;

    unsigned long long keepw[NWORDS];

    #pragma unroll
    for (int w = 0; w < NWORDS; ++w) {
        const int base = w << 6;
        const unsigned long long* rp = mask + (((size_t)b * 1024 + base + l) << 4);
        unsigned long long row[NWORDS];
        #pragma unroll
        for (int p = (w >> 1); p < 8; ++p) {
            ulonglong2 v = *(const ulonglong2*)(rp + (p << 1));
            row[p * 2] = v.x; row[p * 2 + 1] = v.y;
        }
        sdiag[l] = row[w];
        __syncthreads();

        unsigned long long remw = part[w];
        remw |= shflxor_u64(remw, 1);
        remw |= shflxor_u64(remw, 2);
        remw |= shflxor_u64(remw, 4);
        remw |= shflxor_u64(remw, 8);
        remw |= shflxor_u64(remw, 16);
        remw |= shflxor_u64(remw, 32);

        unsigned long long keptm = 0ull;
        unsigned long long valid = vw[w];
        #pragma unroll 8
        for (int jj = 0; jj < 64; ++jj) {
            unsigned long long take = ((valid & ~remw) >> jj) & 1ull;
            keptm |= take << jj;
            remw |= sdiag[jj] & (0ull - take);
        }
        keepw[w] = keptm;

        unsigned long long sel = 0ull - ((keptm >> l) & 1ull);
        #pragma unroll
        for (int w2 = w + 1; w2 < NWORDS; ++w2)
            part[w2] |= row[w2] & sel;
        __syncthreads();
    }

    #pragma unroll
    for (int w = 0; w < NWORDS; ++w) {
        int i = (w << 6) + l;
        if (i < KTOP) {
            int g = b * KTOP + i;
            float fk = (float)((keepw[w] >> l) & 1ull);
            out[g] = tsc[g] * fk;
            out[BATCH * KTOP + g] = (float)clstop[g] * fk;
            const float* bp = boxes + (size_t)g * 5;
            float* op = out + 2 * BATCH * KTOP + (size_t)g * 5;
            op[0] = bp[0] * fk;
            op[1] = bp[1] * fk;
            op[2] = bp[2] * fk;
            op[3] = bp[3] * fk;
            op[4] = bp[4] * fk;
        }
    }
}

extern "C" void kernel_launch(void* const* d_in, const int* in_sizes, int n_in,
                              void* d_out, int out_size, void* d_ws, size_t ws_size,
                              hipStream_t stream) {
    const float* c0 = (const float*)d_in[0];
    const float* c1 = (const float*)d_in[1];
    const float* c2 = (const float*)d_in[2];
    const float* c3 = (const float*)d_in[3];
    const float* c4 = (const float*)d_in[4];
    const float* r0 = (const float*)d_in[5];
    const float* r1 = (const float*)d_in[6];
    const float* r2 = (const float*)d_in[7];
    const float* r3 = (const float*)d_in[8];
    const float* r4 = (const float*)d_in[9];
    const float* t0 = (const float*)d_in[10];
    const float* t1 = (const float*)d_in[11];
    const float* t2 = (const float*)d_in[12];
    const float* t3 = (const float*)d_in[13];
    const float* t4 = (const float*)d_in[14];
    const float* q0 = (const float*)d_in[15];
    const float* q1 = (const float*)d_in[16];
    const float* q2 = (const float*)d_in[17];
    const float* q3 = (const float*)d_in[18];
    const float* q4 = (const float*)d_in[19];

    // Workspace layout, total 5,753,920 B. Aliases safe by stream order:
    //   hist (k_scores→k_findT) aliases mask (k_mask→k_nms)   [findT before mask]
    //   cand (k_compact→k_sortk) aliases boxes (k_decode→...) [sortk before decode]
    char* ws = (char*)d_ws;
    float*              scores  = (float*)(ws + 0);          // 3,142,656
    float*              tsc     = (float*)(ws + 3142656);    //    64,000
    int*                tix     = (int*)(ws + 3206656);      //    64,000
    float*              boxes   = (float*)(ws + 3270656);    //   320,000
    unsigned long long* cand    = (unsigned long long*)(ws + 3270656); // 262,144 alias
    int*                clstop  = (int*)(ws + 3590656);      //    64,000
    unsigned long long* mask    = (unsigned long long*)(ws + 3654656); // 2,097,152
    unsigned int*       hist    = (unsigned int*)(ws + 3654656);       // alias
    int*                tcnt    = (int*)(ws + 5751808);      //     1,024 (16 x 64B)
    int*                tbin    = (int*)(ws + 5752832);      //        64
    float*              out     = (float*)d_out;

    // zero hist + tcnt (contiguous: 2,097,152 + 1,024)
    hipMemsetAsync(ws + 3654656, 0, 2098176, stream);

    k_scores<<<(BATCH * NANCH / 4 + 255) / 256, 256, 0, stream>>>(
        c0, c1, c2, c3, c4, scores, hist);
    k_findT<<<BATCH, 256, 0, stream>>>(hist, tbin);
    k_compact<<<dim3(48, BATCH), 256, 0, stream>>>(scores, tbin, tcnt, cand);
    k_sortk<<<BATCH, 1024, 0, stream>>>(cand, tcnt, tsc, tix);
    k_decode<<<(BATCH * KTOP + 255) / 256, 256, 0, stream>>>(
        c0, c1, c2, c3, c4,
        r0, r1, r2, r3, r4, t0, t1, t2, t3, t4, q0, q1, q2, q3, q4,
        tix, boxes, clstop);
    k_mask<<<dim3(BATCH, 64), 256, 0, stream>>>(boxes, mask);
    k_nms<<<BATCH, 64, 0, stream>>>(mask, tsc, clstop, boxes, out);
}

// Round 6
// 171.715 us; speedup vs baseline: 3.0346x; 1.3761x over previous
//
#include <hip/hip_runtime.h>
#include <stdint.h>

#define NCLS   15
#define NTH    18
#define BATCH  16
#define NANCH  49104
#define KTOP   1000
#define NWORDS 16   // 16*64 = 1024 >= 1000
#define NBIN   32768
#define BSHIFT 15
#define CAND   2048

__device__ __forceinline__ float sigmoidf(float x) {
    return 1.0f / (1.0f + expf(-x));
}

__device__ __forceinline__ void levelOf(int i, int& lvl, int& h, int& s, int& pos) {
    if (i < 36864)      { lvl = 0; h = 192; s = 8;   pos = i; }
    else if (i < 46080) { lvl = 1; h = 96;  s = 16;  pos = i - 36864; }
    else if (i < 48384) { lvl = 2; h = 48;  s = 32;  pos = i - 46080; }
    else if (i < 48960) { lvl = 3; h = 24;  s = 64;  pos = i - 48384; }
    else                { lvl = 4; h = 12;  s = 128; pos = i - 48960; }
}

__device__ __forceinline__ unsigned long long shflxor_u64(unsigned long long v, int m) {
    int lo = __shfl_xor((int)(unsigned int)(v & 0xFFFFFFFFull), m);
    int hi = __shfl_xor((int)(unsigned int)(v >> 32), m);
    return ((unsigned long long)(unsigned int)hi << 32) | (unsigned long long)(unsigned int)lo;
}

// ---- Kernel 1: per-anchor score = sigmoid(max logit), float4 ---------------------
// Histogram via per-block LDS (16-bit packed) + sparse global merge: global
// atomic count drops ~8x and spreads across lines (was: 785K adds on ~100 lines).
__global__ __launch_bounds__(256) void k_scores(
    const float* __restrict__ c0, const float* __restrict__ c1,
    const float* __restrict__ c2, const float* __restrict__ c3,
    const float* __restrict__ c4,
    float* __restrict__ scores, unsigned int* __restrict__ hist)
{
    __shared__ unsigned int lh[NBIN / 2];          // 64 KB, 16-bit packed counts
    const int b = blockIdx.y;
    for (int i = threadIdx.x; i < NBIN / 2; i += 256) lh[i] = 0u;
    __syncthreads();

    #pragma unroll
    for (int r = 0; r < 2; ++r) {
        int f4 = blockIdx.x * 512 + r * 256 + threadIdx.x;
        if (f4 < NANCH / 4) {
            int i = f4 * 4;
            int lvl, h, s, pos;
            levelOf(i, lvl, h, s, pos);
            int hh = h * h;
            const float* cp = (lvl == 0) ? c0 : (lvl == 1) ? c1 : (lvl == 2) ? c2
                              : (lvl == 3) ? c3 : c4;
            const float* base = cp + (size_t)b * NCLS * hh + pos;
            float4 mx = make_float4(-1e30f, -1e30f, -1e30f, -1e30f);
            #pragma unroll
            for (int c = 0; c < NCLS; ++c) {
                float4 v = *(const float4*)(base + (size_t)c * hh);
                mx.x = fmaxf(mx.x, v.x); mx.y = fmaxf(mx.y, v.y);
                mx.z = fmaxf(mx.z, v.z); mx.w = fmaxf(mx.w, v.w);
            }
            float4 sc = make_float4(sigmoidf(mx.x), sigmoidf(mx.y),
                                    sigmoidf(mx.z), sigmoidf(mx.w));
            *(float4*)(scores + (size_t)b * NANCH + i) = sc;
            unsigned int bin;
            bin = __float_as_uint(sc.x) >> BSHIFT;
            atomicAdd(&lh[bin >> 1], 1u << ((bin & 1) << 4));
            bin = __float_as_uint(sc.y) >> BSHIFT;
            atomicAdd(&lh[bin >> 1], 1u << ((bin & 1) << 4));
            bin = __float_as_uint(sc.z) >> BSHIFT;
            atomicAdd(&lh[bin >> 1], 1u << ((bin & 1) << 4));
            bin = __float_as_uint(sc.w) >> BSHIFT;
            atomicAdd(&lh[bin >> 1], 1u << ((bin & 1) << 4));
        }
    }
    __syncthreads();

    unsigned int* hb = hist + (size_t)b * NBIN;
    for (int wd = threadIdx.x; wd < NBIN / 2; wd += 256) {
        unsigned int v = lh[wd];
        if (v) {
            unsigned int lo = v & 0xFFFFu, hi = v >> 16;
            if (lo) atomicAdd(&hb[wd * 2], lo);
            if (hi) atomicAdd(&hb[wd * 2 + 1], hi);
        }
    }
}

// ---- Kernel 2a: find threshold bin per batch (K-th largest), parallel scan ------
__global__ __launch_bounds__(256) void k_findT(
    const unsigned int* __restrict__ hist, int* __restrict__ tbin)
{
    int b = blockIdx.x;
    int tid = threadIdx.x;
    const unsigned int* hb = hist + (size_t)b * NBIN;
    __shared__ unsigned int sc[256];
    __shared__ unsigned int fsc[128];
    __shared__ int s_c, s_t;

    unsigned int s = 0;
    const uint4* hv = (const uint4*)(hb + (size_t)tid * 128);
    #pragma unroll 8
    for (int k = 0; k < 32; ++k) {
        uint4 v = hv[k];
        s += v.x + v.y + v.z + v.w;
    }
    sc[tid] = s;
    if (tid == 0) { s_c = 0; s_t = 0; }
    __syncthreads();
    for (int d = 1; d < 256; d <<= 1) {
        unsigned int add = (tid + d < 256) ? sc[tid + d] : 0;
        __syncthreads();
        sc[tid] += add;
        __syncthreads();
    }
    if (sc[tid] >= (unsigned int)KTOP && (tid == 255 || sc[tid + 1] < (unsigned int)KTOP))
        s_c = tid;
    __syncthreads();
    int c = s_c;
    unsigned int hi = (c < 255) ? sc[c + 1] : 0;
    if (tid < 128) fsc[tid] = hb[c * 128 + tid];
    __syncthreads();
    for (int d = 1; d < 128; d <<= 1) {
        unsigned int add = (tid < 128 && tid + d < 128) ? fsc[tid + d] : 0;
        __syncthreads();
        if (tid < 128) fsc[tid] += add;
        __syncthreads();
    }
    if (tid < 128 && hi + fsc[tid] >= (unsigned int)KTOP &&
        (tid == 127 || hi + fsc[tid + 1] < (unsigned int)KTOP))
        s_t = tid;
    __syncthreads();
    if (tid == 0) tbin[b] = c * 128 + s_t;
}

// ---- Kernel 2b: compact candidates — block-aggregated, padded counters ----------
__global__ __launch_bounds__(256) void k_compact(
    const float* __restrict__ scores, const int* __restrict__ tbin,
    int* __restrict__ cnt, unsigned long long* __restrict__ cand)
{
    const int b = blockIdx.y;
    const int t4 = blockIdx.x * 256 + threadIdx.x;   // float4 index within batch
    __shared__ int lcnt;
    __shared__ int lbase;
    if (threadIdx.x == 0) lcnt = 0;
    __syncthreads();

    const int T = tbin[b];
    const bool in = (t4 < NANCH / 4);
    float4 v = make_float4(0.f, 0.f, 0.f, 0.f);
    if (in) v = *(const float4*)(scores + (size_t)b * NANCH + 4 * (size_t)t4);
    unsigned int bits[4] = { __float_as_uint(v.x), __float_as_uint(v.y),
                             __float_as_uint(v.z), __float_as_uint(v.w) };
    int rank[4];
    #pragma unroll
    for (int k = 0; k < 4; ++k) {
        bool pass = in && ((int)(bits[k] >> BSHIFT) >= T);
        rank[k] = pass ? atomicAdd(&lcnt, 1) : -1;
    }
    __syncthreads();
    if (threadIdx.x == 0) lbase = atomicAdd(&cnt[b * 16], lcnt);
    __syncthreads();
    const int base = lbase;
    #pragma unroll
    for (int k = 0; k < 4; ++k) {
        if (rank[k] >= 0) {
            int p = base + rank[k];
            if (p < CAND) {
                unsigned int idx = 4u * (unsigned int)t4 + (unsigned int)k;
                cand[(size_t)b * CAND + p] =
                    ((unsigned long long)bits[k] << 32) |
                    (unsigned long long)(0xFFFFFFFFu - idx);
            }
        }
    }
}

// ---- Kernel 2c: per-batch bitonic sort of candidates, emit exact top-K ----------
__global__ __launch_bounds__(1024) void k_sortk(
    const unsigned long long* __restrict__ cand, const int* __restrict__ cnt,
    float* __restrict__ tsc, int* __restrict__ tix)
{
    int b = blockIdx.x;
    int tid = threadIdx.x;
    __shared__ unsigned long long keys[CAND];
    int n = cnt[b * 16]; if (n > CAND) n = CAND;
    for (int i = tid; i < CAND; i += 1024)
        keys[i] = (i < n) ? cand[(size_t)b * CAND + i] : 0ull;
    __syncthreads();
    for (int sz = 2; sz <= CAND; sz <<= 1) {
        for (int st = sz >> 1; st > 0; st >>= 1) {
            for (int i = tid; i < CAND; i += 1024) {
                int j = i ^ st;
                if (j > i) {
                    unsigned long long a = keys[i], c = keys[j];
                    bool desc = ((i & sz) == 0);
                    if (desc ? (a < c) : (a > c)) { keys[i] = c; keys[j] = a; }
                }
            }
            __syncthreads();
        }
    }
    if (tid < KTOP) {
        unsigned long long key = keys[tid];
        tsc[b * KTOP + tid] = __uint_as_float((unsigned int)(key >> 32));
        tix[b * KTOP + tid] = (int)(0xFFFFFFFFu - (unsigned int)(key & 0xFFFFFFFFull));
    }
}

// ---- Kernel 3: decode boxes + exact class argmax for selected anchors -----------
__global__ __launch_bounds__(256) void k_decode(
    const float* __restrict__ c0, const float* __restrict__ c1,
    const float* __restrict__ c2, const float* __restrict__ c3,
    const float* __restrict__ c4,
    const float* __restrict__ r0, const float* __restrict__ r1,
    const float* __restrict__ r2, const float* __restrict__ r3,
    const float* __restrict__ r4,
    const float* __restrict__ t0, const float* __restrict__ t1,
    const float* __restrict__ t2, const float* __restrict__ t3,
    const float* __restrict__ t4,
    const float* __restrict__ q0, const float* __restrict__ q1,
    const float* __restrict__ q2, const float* __restrict__ q3,
    const float* __restrict__ q4,
    const int* __restrict__ tix, float* __restrict__ boxes, int* __restrict__ clstop)
{
    int g = blockIdx.x * 256 + threadIdx.x;
    if (g >= BATCH * KTOP) return;
    int b = g / KTOP;
    int idx = tix[g];
    int lvl, h, s, pos;
    levelOf(idx, lvl, h, s, pos);
    int y = pos / h, x = pos - y * h;
    int hh = h * h;
    const float* cp = (lvl == 0) ? c0 : (lvl == 1) ? c1 : (lvl == 2) ? c2 : (lvl == 3) ? c3 : c4;
    const float* rp = (lvl == 0) ? r0 : (lvl == 1) ? r1 : (lvl == 2) ? r2 : (lvl == 3) ? r3 : r4;
    const float* tp = (lvl == 0) ? t0 : (lvl == 1) ? t1 : (lvl == 2) ? t2 : (lvl == 3) ? t3 : t4;
    const float* qp = (lvl == 0) ? q0 : (lvl == 1) ? q1 : (lvl == 2) ? q2 : (lvl == 3) ? q3 : q4;
    int off = y * h + x;

    const float* cb = cp + (size_t)b * NCLS * hh + off;
    float bestc = -1e30f; int bc = 0;
    #pragma unroll
    for (int c = 0; c < NCLS; ++c) {
        float v = sigmoidf(cb[(size_t)c * hh]);
        if (v > bestc) { bestc = v; bc = c; }
    }
    clstop[g] = bc + 1;

    const float* tb = tp + (size_t)b * NTH * hh + off;
    float best = -1e30f; int bt = 0;
    #pragma unroll
    for (int c = 0; c < NTH; ++c) {
        float v = sigmoidf(tb[(size_t)c * hh]);
        if (v > best) { best = v; bt = c; }
    }
    float theta = (float)(bt + 1) * 10.0f + qp[(size_t)b * hh + off];

    const float* rb = rp + (size_t)b * 5 * hh + off;
    float fs = (float)s;
    float rr0 = rb[0] * fs;
    float rr1 = rb[(size_t)hh] * fs;
    float rr2 = rb[(size_t)2 * hh] * fs;
    float rr3 = rb[(size_t)3 * hh] * fs;
    float cx = (float)(x * s + (s >> 1));
    float cy = (float)(y * s + (s >> 1));
    float* op = boxes + (size_t)g * 5;
    op[0] = cx - rr0;
    op[1] = cy - rr1;
    op[2] = cx + rr2;
    op[3] = cy + rr3;
    op[4] = theta;
}

// ---- Kernel 4a: suppression bitmask, ROW-major [b][1024][16] ---------------------
__global__ __launch_bounds__(256) void k_mask(
    const float* __restrict__ boxes, unsigned long long* __restrict__ mask)
{
    int b = blockIdx.x;
    __shared__ float bx1[KTOP], by1[KTOP], bx2[KTOP], by2[KTOP], bar[KTOP];
    for (int r = threadIdx.x; r < KTOP; r += 256) {
        const float* p = boxes + ((size_t)(b * KTOP + r)) * 5;
        float x1 = p[0], y1 = p[1], x2 = p[2], y2 = p[3];
        bx1[r] = x1; by1[r] = y1; bx2[r] = x2; by2[r] = y2;
        bar[r] = fmaxf(x2 - x1, 0.0f) * fmaxf(y2 - y1, 0.0f);
    }
    __syncthreads();
    int i = (blockIdx.y << 4) + (threadIdx.x >> 4);
    int w = threadIdx.x & 15;
    int j0 = w << 6;
    int lo = (j0 > i + 1) ? j0 : (i + 1);
    int hi = (j0 + 64 < KTOP) ? (j0 + 64) : KTOP;
    unsigned long long m = 0ull;
    if (i < KTOP && lo < hi) {
        float x1 = bx1[i], y1 = by1[i], x2 = bx2[i], y2 = by2[i], ai = bar[i];
        for (int j = lo; j < hi; ++j) {
            float iw = fminf(x2, bx2[j]) - fmaxf(x1, bx1[j]);
            iw = fmaxf(iw, 0.0f);
            float ih = fminf(y2, by2[j]) - fmaxf(y1, by1[j]);
            ih = fmaxf(ih, 0.0f);
            float inter = iw * ih;
            float u = ai + bar[j] - inter;
            float iou = inter / fmaxf(u, 1e-8f);
            if (iou > 0.3f) m |= (1ull << (j - j0));
        }
    }
    mask[(((size_t)b * 1024 + i) << 4) + w] = m;
}

// ---- Kernel 4b: greedy NMS, one wave per batch, register-chain + fused output ---
__global__ __launch_bounds__(64) void k_nms(
    const unsigned long long* __restrict__ mask,   // [b][1024][16]
    const float* __restrict__ tsc, const int* __restrict__ clstop,
    const float* __restrict__ boxes, float* __restrict__ out)
{
    const int b = blockIdx.x;
    const int l = threadIdx.x;
    __shared__ unsigned long long sdiag[64];

    unsigned long long vw[NWORDS];
    #pragma unroll
    for (int w = 0; w < NWORDS; ++w) {
        int i = (w << 6) + l;
        bool v = (i < KTOP) && (tsc[b * KTOP + i] >= 0.05f);
        vw[w] = __ballot(v);
    }

    unsigned long long part[NWORDS];
    #pragma unroll
    for (int w = 0; w < NWORDS; ++w) part[w] = 0ull;

    unsigned long long keepw[NWORDS];

    #pragma unroll
    for (int w = 0; w < NWORDS; ++w) {
        const int base = w << 6;
        const unsigned long long* rp = mask + (((size_t)b * 1024 + base + l) << 4);
        unsigned long long row[NWORDS];
        #pragma unroll
        for (int p = (w >> 1); p < 8; ++p) {
            ulonglong2 v = *(const ulonglong2*)(rp + (p << 1));
            row[p * 2] = v.x; row[p * 2 + 1] = v.y;
        }
        sdiag[l] = row[w];
        __syncthreads();

        unsigned long long remw = part[w];
        remw |= shflxor_u64(remw, 1);
        remw |= shflxor_u64(remw, 2);
        remw |= shflxor_u64(remw, 4);
        remw |= shflxor_u64(remw, 8);
        remw |= shflxor_u64(remw, 16);
        remw |= shflxor_u64(remw, 32);

        unsigned long long keptm = 0ull;
        unsigned long long valid = vw[w];
        #pragma unroll 8
        for (int jj = 0; jj < 64; ++jj) {
            unsigned long long take = ((valid & ~remw) >> jj) & 1ull;
            keptm |= take << jj;
            remw |= sdiag[jj] & (0ull - take);
        }
        keepw[w] = keptm;

        unsigned long long sel = 0ull - ((keptm >> l) & 1ull);
        #pragma unroll
        for (int w2 = w + 1; w2 < NWORDS; ++w2)
            part[w2] |= row[w2] & sel;
        __syncthreads();
    }

    #pragma unroll
    for (int w = 0; w < NWORDS; ++w) {
        int i = (w << 6) + l;
        if (i < KTOP) {
            int g = b * KTOP + i;
            float fk = (float)((keepw[w] >> l) & 1ull);
            out[g] = tsc[g] * fk;
            out[BATCH * KTOP + g] = (float)clstop[g] * fk;
            const float* bp = boxes + (size_t)g * 5;
            float* op = out + 2 * BATCH * KTOP + (size_t)g * 5;
            op[0] = bp[0] * fk;
            op[1] = bp[1] * fk;
            op[2] = bp[2] * fk;
            op[3] = bp[3] * fk;
            op[4] = bp[4] * fk;
        }
    }
}

extern "C" void kernel_launch(void* const* d_in, const int* in_sizes, int n_in,
                              void* d_out, int out_size, void* d_ws, size_t ws_size,
                              hipStream_t stream) {
    const float* c0 = (const float*)d_in[0];
    const float* c1 = (const float*)d_in[1];
    const float* c2 = (const float*)d_in[2];
    const float* c3 = (const float*)d_in[3];
    const float* c4 = (const float*)d_in[4];
    const float* r0 = (const float*)d_in[5];
    const float* r1 = (const float*)d_in[6];
    const float* r2 = (const float*)d_in[7];
    const float* r3 = (const float*)d_in[8];
    const float* r4 = (const float*)d_in[9];
    const float* t0 = (const float*)d_in[10];
    const float* t1 = (const float*)d_in[11];
    const float* t2 = (const float*)d_in[12];
    const float* t3 = (const float*)d_in[13];
    const float* t4 = (const float*)d_in[14];
    const float* q0 = (const float*)d_in[15];
    const float* q1 = (const float*)d_in[16];
    const float* q2 = (const float*)d_in[17];
    const float* q3 = (const float*)d_in[18];
    const float* q4 = (const float*)d_in[19];

    // Workspace layout, total 5,753,920 B. Aliases safe by stream order:
    //   hist (k_scores→k_findT) aliases mask (k_mask→k_nms)   [findT before mask]
    //   cand (k_compact→k_sortk) aliases boxes (k_decode→...) [sortk before decode]
    char* ws = (char*)d_ws;
    float*              scores  = (float*)(ws + 0);          // 3,142,656
    float*              tsc     = (float*)(ws + 3142656);    //    64,000
    int*                tix     = (int*)(ws + 3206656);      //    64,000
    float*              boxes   = (float*)(ws + 3270656);    //   320,000
    unsigned long long* cand    = (unsigned long long*)(ws + 3270656); // 262,144 alias
    int*                clstop  = (int*)(ws + 3590656);      //    64,000
    unsigned long long* mask    = (unsigned long long*)(ws + 3654656); // 2,097,152
    unsigned int*       hist    = (unsigned int*)(ws + 3654656);       // alias
    int*                tcnt    = (int*)(ws + 5751808);      //     1,024 (16 x 64B)
    int*                tbin    = (int*)(ws + 5752832);      //        64
    float*              out     = (float*)d_out;

    // zero hist + tcnt (contiguous: 2,097,152 + 1,024)
    hipMemsetAsync(ws + 3654656, 0, 2098176, stream);

    k_scores<<<dim3(24, BATCH), 256, 0, stream>>>(
        c0, c1, c2, c3, c4, scores, hist);
    k_findT<<<BATCH, 256, 0, stream>>>(hist, tbin);
    k_compact<<<dim3(48, BATCH), 256, 0, stream>>>(scores, tbin, tcnt, cand);
    k_sortk<<<BATCH, 1024, 0, stream>>>(cand, tcnt, tsc, tix);
    k_decode<<<(BATCH * KTOP + 255) / 256, 256, 0, stream>>>(
        c0, c1, c2, c3, c4,
        r0, r1, r2, r3, r4, t0, t1, t2, t3, t4, q0, q1, q2, q3, q4,
        tix, boxes, clstop);
    k_mask<<<dim3(BATCH, 64), 256, 0, stream>>>(boxes, mask);
    k_nms<<<BATCH, 64, 0, stream>>>(mask, tsc, clstop, boxes, out);
}